// Round 7
// baseline (1015.055 us; speedup 1.0000x reference)
//
#include <hip/hip_runtime.h>
#include <hip/hip_bf16.h>
#include <cstdint>

// ---------------------------------------------------------------------------
// LSTM cell fused forward on MI355X (gfx950).
//   gates = [input|hidden] @ [W;U] + b, fp32 via 3-product bf16 emulation
//   realized as ONE bf16 GEMM with virtual K'=6144 (3 segments, no dup):
//     k' in [0,2048)    : Ahi x Bhi
//     k' in [2048,4096) : Ahi x Blo
//     k' in [4096,6144) : Alo x Bhi
//   gate GEMM = m201 8-phase 256^2 template (BK=64, 8 waves, 16x16x32,
//   st_16x32 swizzle, counted vmcnt, setprio), fused LSTM epilogue.
//   logits = h_new @ W_h + b_h  (128^2 bf16x3 GEMM), log_softmax row-wise.
// ---------------------------------------------------------------------------

#define B_DIM   8192
#define K1      2048
#define H_DIM   1024

typedef __attribute__((ext_vector_type(8))) __bf16 bf16x8;
typedef __attribute__((ext_vector_type(4))) float  f32x4;

__device__ __forceinline__ unsigned short f2bf(float f) {
    unsigned int u = __float_as_uint(f);
    u += 0x7FFFu + ((u >> 16) & 1u);
    return (unsigned short)(u >> 16);
}
__device__ __forceinline__ float bf2f(unsigned short s) {
    return __uint_as_float(((unsigned int)s) << 16);
}

__device__ __forceinline__ void gload_lds16(const void* g, void* l) {
    __builtin_amdgcn_global_load_lds(
        (const __attribute__((address_space(1))) void*)g,
        (__attribute__((address_space(3))) void*)l, 16, 0, 0);
}

__device__ __forceinline__ unsigned lds_off(const void* p) {
    return (unsigned)(uintptr_t)(const __attribute__((address_space(3))) void*)p;
}

#define DSR1(dst, addr)                                                      \
    asm volatile("ds_read_b128 %0, %1" : "=v"(dst) : "v"(addr))

__device__ __forceinline__ f32x4 mfma16(bf16x8 a, bf16x8 b, f32x4 c) {
    return __builtin_amdgcn_mfma_f32_16x16x32_bf16(a, b, c, 0, 0, 0);
}

#define SCHED0() __builtin_amdgcn_sched_barrier(0)

// ---------------------------------------------------------------------------
// Split X = [input | hidden] (row-major [8192][2048]) into bf16 hi/lo.
// ---------------------------------------------------------------------------
__global__ __launch_bounds__(256) void k_split_x(
    const float* __restrict__ input, const float* __restrict__ hidden,
    unsigned short* __restrict__ xhi, unsigned short* __restrict__ xlo) {
    const int64_t n4 = (int64_t)B_DIM * K1 / 4;
    for (int64_t i = (int64_t)blockIdx.x * blockDim.x + threadIdx.x; i < n4;
         i += (int64_t)gridDim.x * blockDim.x) {
        int64_t e = i * 4;
        int row = (int)(e >> 11);
        int col = (int)(e & 2047);
        const float* src = (col < 1024) ? (input + (int64_t)row * 1024 + col)
                                        : (hidden + (int64_t)row * 1024 + (col - 1024));
        float4 v = *(const float4*)src;
        ushort4 hv, lv;
        hv.x = f2bf(v.x); lv.x = f2bf(v.x - bf2f(hv.x));
        hv.y = f2bf(v.y); lv.y = f2bf(v.y - bf2f(hv.y));
        hv.z = f2bf(v.z); lv.z = f2bf(v.z - bf2f(hv.z));
        hv.w = f2bf(v.w); lv.w = f2bf(v.w - bf2f(hv.w));
        *(ushort4*)(xhi + e) = hv;
        *(ushort4*)(xlo + e) = lv;
    }
}

// ---------------------------------------------------------------------------
// Transpose + split [1024x1024] weight into row-major [n'][dstK] hi/lo at
// n' = h*nmul + ng, k = koff + klocal.
// ---------------------------------------------------------------------------
__global__ __launch_bounds__(256) void k_trans_split(
    const float* __restrict__ src,
    unsigned short* __restrict__ dhi, unsigned short* __restrict__ dlo,
    int nmul, int ng, int dstK, int koff) {
    __shared__ float t[64][65];
    const int h0 = blockIdx.x * 64;
    const int k0 = blockIdx.y * 64;
    const int tx = threadIdx.x & 63, ty = threadIdx.x >> 6;
    #pragma unroll
    for (int r = ty; r < 64; r += 4)
        t[r][tx] = src[(int64_t)(k0 + r) * 1024 + h0 + tx];
    __syncthreads();
    #pragma unroll
    for (int r = ty; r < 64; r += 4) {
        float v = t[tx][r];
        unsigned short hi = f2bf(v);
        unsigned short lo = f2bf(v - bf2f(hi));
        int64_t o = (int64_t)((h0 + r) * nmul + ng) * dstK + koff + k0 + tx;
        dhi[o] = hi;
        dlo[o] = lo;
    }
}

// bias4[n'] = b_g[h], n' = 4h+g
__global__ __launch_bounds__(256) void k_pack_bias(
    const float* __restrict__ bf_, const float* __restrict__ bi_,
    const float* __restrict__ bc_, const float* __restrict__ bo_,
    float* __restrict__ bias4) {
    int n = blockIdx.x * 256 + threadIdx.x;
    if (n < 4096) {
        int g = n & 3, h = n >> 2;
        const float* p = (g == 0) ? bf_ : (g == 1) ? bi_ : (g == 2) ? bc_ : bo_;
        bias4[n] = p[h];
    }
}

// ---------------------------------------------------------------------------
// GATE GEMM: m201 8-phase template. 256x256 tile, BK=64, 8 waves (2Mx4N),
// virtual K'=6144 via segment map.  LDS: 2 buf x (A 32KB + B 32KB) = 128KB,
// st_16x32 swizzle (byte ^= ((row>>2)&1)<<5), pre-swizzled global source,
// swizzled ds_read.  Counted vmcnt at phases 4/8; lgkmcnt(8) throttle on
// 12-read phases; B-frags persist in regs across phases.
// ---------------------------------------------------------------------------
#define NTILE 96   // K'/64
#define NIT   48   // NTILE/2

__global__ __launch_bounds__(512, 2) void k_gate_gemm(
    const char* __restrict__ Ahi, const char* __restrict__ Alo,
    const char* __restrict__ Bhi, const char* __restrict__ Blo,
    const float* __restrict__ bias,
    const float* __restrict__ cell,
    float* __restrict__ out0,
    unsigned short* __restrict__ hhi, unsigned short* __restrict__ hlo) {
    extern __shared__ char smem[];  // 131072

    const int tid  = threadIdx.x;
    const int lane = tid & 63;
    const int w    = tid >> 6;          // wave 0..7
    const int wr   = (w >> 2) * 128;    // wave M offset
    const int wc   = (w & 3) * 64;      // wave N offset
    const int fr   = lane & 15;
    const int q    = lane >> 4;

    // XCD-aware swizzle: 512 blocks, 512%8==0
    const int bid = blockIdx.x;
    const int swz = (bid & 7) * 64 + (bid >> 3);
    const int m0  = (swz >> 4) * 256;   // 32 m-panels
    const int n0  = (swz & 15) * 256;   // 16 n-panels

    f32x4 acc[8][4];
    #pragma unroll
    for (int i = 0; i < 8; i++)
        #pragma unroll
        for (int j = 0; j < 4; j++) acc[i][j] = (f32x4){0.f, 0.f, 0.f, 0.f};

    // ---- staging geometry (pre-swizzled global source, linear LDS dest) ----
    const int thRow = tid >> 3;                                  // 0..63
    const int thK   = ((tid & 7) * 16) ^ (((tid >> 5) & 1) << 5);  // 16B, swz

    // STG: one half-tile (128 rows x 64 k) = 2 gload calls per wave.
    auto STG = [&](int isB, int h, int tt, unsigned bufOff) {
        const char* seg;
        const int sg = tt >> 5, tl = tt & 31;
        if (!isB) seg = (sg == 2) ? Alo : Ahi;
        else      seg = (sg == 0) ? Bhi : (sg == 1) ? Blo : Bhi;
        const int rowb = (isB ? n0 : m0) + h * 128 + thRow;
        const char* src = seg + (int64_t)rowb * 4096 + tl * 128 + thK;
        char* dst = smem + bufOff + isB * 32768 + h * 16384 + w * 1024;
        gload_lds16(src, dst);
        gload_lds16(src + (int64_t)64 * 4096, dst + 8192);
    };

    // ---- ds_read bases (swizzle: ^((fr>>2)&1)<<5 on the k-byte) ----
    const unsigned ldsBase = lds_off(smem);
    const unsigned kSw  = (unsigned)((q * 16) ^ (((fr >> 2) & 1) << 5));
    const unsigned aB0  = ldsBase + (unsigned)((wr + fr) * 128) + kSw;
    const unsigned bB0  = ldsBase + 32768u + (unsigned)((wc + fr) * 128) + kSw;

    bf16x8 a[4][2];
    bf16x8 b[2][2][2];   // [qn][nf][ks]

    auto RA = [&](unsigned base, int qm) {
        #pragma unroll
        for (int mf = 0; mf < 4; mf++)
            #pragma unroll
            for (int ks = 0; ks < 2; ks++)
                DSR1(a[mf][ks], base + (unsigned)(qm * 8192 + mf * 2048 + ks * 64));
    };
    auto RB = [&](unsigned base, int qn) {
        #pragma unroll
        for (int nf = 0; nf < 2; nf++)
            #pragma unroll
            for (int ks = 0; ks < 2; ks++)
                DSR1(b[qn][nf][ks], base + (unsigned)(qn * 4096 + nf * 2048 + ks * 64));
    };
    auto MF = [&](int qm, int qn) {
        __builtin_amdgcn_s_setprio(1);
        #pragma unroll
        for (int ks = 0; ks < 2; ks++)
            #pragma unroll
            for (int mf = 0; mf < 4; mf++)
                #pragma unroll
                for (int nf = 0; nf < 2; nf++)
                    acc[qm * 4 + mf][qn * 2 + nf] =
                        mfma16(a[mf][ks], b[qn][nf][ks], acc[qm * 4 + mf][qn * 2 + nf]);
        __builtin_amdgcn_s_setprio(0);
    };

#define BAR_LGKM()                                                  \
    SCHED0();                                                       \
    __builtin_amdgcn_s_barrier();                                   \
    asm volatile("s_waitcnt lgkmcnt(0)" ::: "memory");              \
    SCHED0();

#define ENDBAR()                                                    \
    SCHED0();                                                       \
    __builtin_amdgcn_s_barrier();                                   \
    SCHED0();

    // ---- prologue: T0 fully + T1's B halves; confirm T0 ----
    STG(1, 0, 0, 0); STG(1, 1, 0, 0);
    STG(0, 0, 0, 0); STG(0, 1, 0, 0);
    STG(1, 0, 1, 65536); STG(1, 1, 1, 65536);
    asm volatile("s_waitcnt vmcnt(4)" ::: "memory");
    ENDBAR();

    #pragma unroll 1
    for (int i = 0; i < NIT; ++i) {
        const int T1 = 2 * i + 1, t2 = 2 * i + 2, t3 = 2 * i + 3;
        const bool more = (i < NIT - 1);

        // ---- p0: read A(qm0)+B(qn0) of buf0; stage A0(T1)->buf1 ----
        RA(aB0, 0); RB(bB0, 0);
        STG(0, 0, T1, 65536);
        asm volatile("s_waitcnt lgkmcnt(8)" ::: "memory");
        BAR_LGKM();
        MF(0, 0);
        ENDBAR();

        // ---- p1: read B(qn1) of buf0; stage A1(T1)->buf1 ----
        RB(bB0, 1);
        STG(0, 1, T1, 65536);
        BAR_LGKM();
        MF(0, 1);
        ENDBAR();

        // ---- p2: read A(qm1) of buf0; stage B0(t2)->buf0 ----
        RA(aB0, 1);
        if (more) STG(1, 0, t2, 0);
        BAR_LGKM();
        MF(1, 0);
        ENDBAR();

        // ---- p3: stage B1(t2)->buf0; MFMA; vmcnt ----
        if (more) STG(1, 1, t2, 0);
        BAR_LGKM();
        MF(1, 1);
        SCHED0();
        if (more) { asm volatile("s_waitcnt vmcnt(4)" ::: "memory"); }
        else      { asm volatile("s_waitcnt vmcnt(0)" ::: "memory"); }
        ENDBAR();

        // ---- p4: read A(qm0)+B(qn0) of buf1; stage A0(t2)->buf0 ----
        RA(aB0 + 65536u, 0); RB(bB0 + 65536u, 0);
        if (more) STG(0, 0, t2, 0);
        asm volatile("s_waitcnt lgkmcnt(8)" ::: "memory");
        BAR_LGKM();
        MF(0, 0);
        ENDBAR();

        // ---- p5: read B(qn1) of buf1; stage A1(t2)->buf0 ----
        RB(bB0 + 65536u, 1);
        if (more) STG(0, 1, t2, 0);
        BAR_LGKM();
        MF(0, 1);
        ENDBAR();

        // ---- p6: read A(qm1) of buf1; stage B0(t3)->buf1 ----
        RA(aB0 + 65536u, 1);
        if (more) STG(1, 0, t3, 65536);
        BAR_LGKM();
        MF(1, 0);
        ENDBAR();

        // ---- p7: stage B1(t3)->buf1; MFMA; vmcnt ----
        if (more) STG(1, 1, t3, 65536);
        BAR_LGKM();
        MF(1, 1);
        SCHED0();
        if (more) { asm volatile("s_waitcnt vmcnt(4)" ::: "memory"); }
        else      { asm volatile("s_waitcnt vmcnt(0)" ::: "memory"); }
        ENDBAR();
    }

#undef BAR_LGKM
#undef ENDBAR

    // ---- fused LSTM epilogue (16x16 C layout: col=lane&15, row=q*4+j) ----
    const int lb = lane & ~3;   // quad lanes lb..lb+3 = gates f,i,c,o of one h
    const int64_t OFF_H = (int64_t)B_DIM * H_DIM;
    const int64_t OFF_C = (int64_t)2 * B_DIM * H_DIM;
    const int g = lane & 3;
    #pragma unroll
    for (int fm = 0; fm < 8; fm++)
        #pragma unroll
        for (int fn = 0; fn < 4; fn++) {
            int col = n0 + wc + fn * 16 + fr;   // n' = 4h+g
            int h = col >> 2;
            float bb = bias[col];
            int rowb = m0 + wr + fm * 16 + q * 4;
            #pragma unroll
            for (int j = 0; j < 4; j++) {
                float v = acc[fm][fn][j] + bb;
                float a1 = (g == 2) ? tanhf(v) : 1.0f / (1.0f + expf(-v));
                float fg = __shfl(a1, lb + 0, 64);
                float ig = __shfl(a1, lb + 1, 64);
                float ct = __shfl(a1, lb + 2, 64);
                float og = __shfl(a1, lb + 3, 64);
                int row = rowb + j;
                int64_t o = (int64_t)row * H_DIM + h;
                float cn = fg * cell[o] + ig * ct;
                float hn = og * tanhf(cn);
                if (g == 0) {
                    out0[OFF_C + o] = cn;
                } else if (g == 1) {
                    out0[OFF_H + o] = hn;
                } else if (g == 2) {
                    hhi[o] = f2bf(hn);
                } else {
                    unsigned short tt = f2bf(hn);
                    hlo[o] = f2bf(hn - bf2f(tt));
                }
            }
        }
}

// ---------------------------------------------------------------------------
// LOGITS GEMM: bf16x3, 128x128 tile, BK=32, 4 waves (m97 structure).
// ---------------------------------------------------------------------------
__global__ __launch_bounds__(256, 2) void k_gemm128(
    const unsigned short* __restrict__ Ahi, const unsigned short* __restrict__ Alo,
    const unsigned short* __restrict__ Bhi, const unsigned short* __restrict__ Blo,
    int K, int Ncols,
    const float* __restrict__ bias,
    float* __restrict__ out0) {
    __shared__ char smem[32768];

    const int tid  = threadIdx.x;
    const int lane = tid & 63;
    const int w    = tid >> 6;
    const int wr   = (w >> 1) * 64;
    const int wc   = (w & 1) * 64;
    const int m0   = blockIdx.y * 128;
    const int n0   = blockIdx.x * 128;

    f32x4 acc[4][4];
    #pragma unroll
    for (int i = 0; i < 4; i++)
        #pragma unroll
        for (int j = 0; j < 4; j++) acc[i][j] = (f32x4){0.f, 0.f, 0.f, 0.f};

    const int sr = tid >> 3;
    const int s2 = (tid & 7) ^ (sr & 7);
    const unsigned short* Asrc =
        ((s2 < 4) ? Ahi : Alo) + (int64_t)(m0 + sr) * K + (s2 & 3) * 8;
    const unsigned short* Bsrc =
        ((s2 < 4) ? Bhi : Blo) + (int64_t)(n0 + sr) * K + (s2 & 3) * 8;

    const int q  = lane >> 4;
    const int fr = lane & 15;
    const int sw = lane & 7;
    const int hiSlot = (q ^ sw) << 4;
    const int loSlot = ((q + 4) ^ sw) << 4;

    for (int kt = 0; kt < K; kt += 32) {
        __syncthreads();
        #pragma unroll
        for (int i = 0; i < 4; i++) {
            gload_lds16(Asrc + (int64_t)i * 32 * K + kt, smem + i * 4096 + w * 1024);
            gload_lds16(Bsrc + (int64_t)i * 32 * K + kt, smem + 16384 + i * 4096 + w * 1024);
        }
        __syncthreads();

        bf16x8 ah[4], al[4], bh[4], bl[4];
        #pragma unroll
        for (int mi = 0; mi < 4; mi++) {
            const char* rp = smem + (wr + mi * 16 + fr) * 128;
            ah[mi] = *(const bf16x8*)(rp + hiSlot);
            al[mi] = *(const bf16x8*)(rp + loSlot);
        }
        #pragma unroll
        for (int ni = 0; ni < 4; ni++) {
            const char* rp = smem + 16384 + (wc + ni * 16 + fr) * 128;
            bh[ni] = *(const bf16x8*)(rp + hiSlot);
            bl[ni] = *(const bf16x8*)(rp + loSlot);
        }
        #pragma unroll
        for (int mi = 0; mi < 4; mi++)
            #pragma unroll
            for (int ni = 0; ni < 4; ni++) {
                acc[mi][ni] = mfma16(ah[mi], bh[ni], acc[mi][ni]);
                acc[mi][ni] = mfma16(ah[mi], bl[ni], acc[mi][ni]);
                acc[mi][ni] = mfma16(al[mi], bh[ni], acc[mi][ni]);
            }
    }

    #pragma unroll
    for (int mi = 0; mi < 4; mi++)
        #pragma unroll
        for (int ni = 0; ni < 4; ni++) {
            int col = n0 + wc + ni * 16 + fr;
            int rowb = m0 + wr + mi * 16 + q * 4;
            float bb = bias[col];
            #pragma unroll
            for (int j = 0; j < 4; j++)
                out0[(int64_t)(rowb + j) * Ncols + col] = acc[mi][ni][j] + bb;
        }
}

// ---------------------------------------------------------------------------
// Row-wise log_softmax over [8192][1024]: one block per row.
// ---------------------------------------------------------------------------
__global__ __launch_bounds__(256) void k_logsoftmax(
    const float* __restrict__ logits, float* __restrict__ out) {
    const int row = blockIdx.x;
    const int t = threadIdx.x;
    const float* x = logits + (int64_t)row * 1024;
    float4 v = *(const float4*)(x + t * 4);

    float m = fmaxf(fmaxf(v.x, v.y), fmaxf(v.z, v.w));
    #pragma unroll
    for (int off = 1; off < 64; off <<= 1) m = fmaxf(m, __shfl_xor(m, off, 64));
    __shared__ float sm[4];
    __shared__ float ssum[4];
    int ln = t & 63, wv = t >> 6;
    if (ln == 0) sm[wv] = m;
    __syncthreads();
    m = fmaxf(fmaxf(sm[0], sm[1]), fmaxf(sm[2], sm[3]));

    float s = expf(v.x - m) + expf(v.y - m) + expf(v.z - m) + expf(v.w - m);
    #pragma unroll
    for (int off = 1; off < 64; off <<= 1) s += __shfl_xor(s, off, 64);
    if (ln == 0) ssum[wv] = s;
    __syncthreads();
    s = ssum[0] + ssum[1] + ssum[2] + ssum[3];

    float lse = m + logf(s);
    float4 o;
    o.x = v.x - lse; o.y = v.y - lse; o.z = v.z - lse; o.w = v.w - lse;
    *(float4*)(out + (int64_t)row * 1024 + t * 4) = o;
}

// ---------------------------------------------------------------------------
extern "C" void kernel_launch(void* const* d_in, const int* in_sizes, int n_in,
                              void* d_out, int out_size, void* d_ws, size_t ws_size,
                              hipStream_t stream) {
    const float* input  = (const float*)d_in[0];
    const float* hidden = (const float*)d_in[1];
    const float* cell   = (const float*)d_in[2];
    const float* W_f = (const float*)d_in[3];
    const float* U_f = (const float*)d_in[4];
    const float* b_f = (const float*)d_in[5];
    const float* W_i = (const float*)d_in[6];
    const float* U_i = (const float*)d_in[7];
    const float* b_i = (const float*)d_in[8];
    const float* W_c = (const float*)d_in[9];
    const float* U_c = (const float*)d_in[10];
    const float* b_c = (const float*)d_in[11];
    const float* W_o = (const float*)d_in[12];
    const float* U_o = (const float*)d_in[13];
    const float* b_o = (const float*)d_in[14];
    const float* W_h = (const float*)d_in[15];
    const float* b_h = (const float*)d_in[16];
    float* out = (float*)d_out;

    char* ws = (char*)d_ws;
    unsigned short* xhi  = (unsigned short*)(ws);               // 32 MB
    unsigned short* xlo  = (unsigned short*)(ws + 33554432);    // 32 MB
    unsigned short* wuhi = (unsigned short*)(ws + 67108864);    // 16 MB
    unsigned short* wulo = (unsigned short*)(ws + 83886080);    // 16 MB
    unsigned short* hhi  = (unsigned short*)(ws + 100663296);   // 16 MB
    unsigned short* hlo  = (unsigned short*)(ws + 117440512);   // 16 MB
    unsigned short* whhi = (unsigned short*)(ws + 134217728);   // 2 MB
    unsigned short* whlo = (unsigned short*)(ws + 136314880);   // 2 MB
    float*          bias4 = (float*)(ws + 138412032);           // 16 KB
    float*          logits = (float*)(ws);                      // aliases X
    if (ws_size < (size_t)138428416) return;

    hipFuncSetAttribute((const void*)k_gate_gemm,
                        hipFuncAttributeMaxDynamicSharedMemorySize, 131072);

    k_split_x<<<2048, 256, 0, stream>>>(input, hidden, xhi, xlo);

    const float* Warr[8] = {W_f, W_i, W_c, W_o, U_f, U_i, U_c, U_o};
    for (int a = 0; a < 8; a++)
        k_trans_split<<<dim3(16, 16), 256, 0, stream>>>(
            Warr[a], wuhi, wulo, 4, a & 3, 2048, (a >> 2) * 1024);
    k_trans_split<<<dim3(16, 16), 256, 0, stream>>>(W_h, whhi, whlo, 1, 0, 1024, 0);
    k_pack_bias<<<16, 256, 0, stream>>>(b_f, b_i, b_c, b_o, bias4);

    // gates GEMM + fused LSTM epilogue: M=8192, N'=4096, K'=6144, 512 blocks
    k_gate_gemm<<<512, 512, 131072, stream>>>(
        (const char*)xhi, (const char*)xlo, (const char*)wuhi, (const char*)wulo,
        bias4, cell, out, hhi, hlo);

    // logits GEMM: M=8192, N=1024, K=1024
    k_gemm128<<<dim3(8, 64), 256, 0, stream>>>(
        hhi, hlo, whhi, whlo, 1024, 1024, b_h, logits);

    k_logsoftmax<<<8192, 256, 0, stream>>>(logits, out);
}

// Round 10
// 497.592 us; speedup vs baseline: 2.0399x; 2.0399x over previous
//
#include <hip/hip_runtime.h>
#include <hip/hip_bf16.h>
#include <cstdint>

// ---------------------------------------------------------------------------
// LSTM cell fused forward on MI355X (gfx950).
//   gates = [input|hidden] @ [W;U] + b  -- fp32 via fp16 2-product emulation:
//     x*W ~= x_hi*W_hi + x_lo*W_hi   (A to ~22 bits, W fp16-quantized)
//   gate GEMM: R2-proven 256^2 / BK=32 / 8-wave / 4-phase / counted-vmcnt
//   elementwise LSTM epilogue fused; logits = h @ W_h + b_h (same 2-product);
//   log_softmax row-wise.
// ---------------------------------------------------------------------------

#define B_DIM   8192
#define K1      2048
#define H_DIM   1024
#define NT      64        // K1/32
#define BUF     49152     // A 32KB + B(hi) 16KB per buffer

typedef __attribute__((ext_vector_type(8))) _Float16 f16x8;
typedef __attribute__((ext_vector_type(4))) float    f32x4;

__device__ __forceinline__ unsigned short f2h_bits(float x) {
    _Float16 h = (_Float16)x;
    return __builtin_bit_cast(unsigned short, h);
}
__device__ __forceinline__ float h2f_bits(unsigned short b) {
    return (float)__builtin_bit_cast(_Float16, b);
}

__device__ __forceinline__ void gload_lds16(const void* g, void* l) {
    __builtin_amdgcn_global_load_lds(
        (const __attribute__((address_space(1))) void*)g,
        (__attribute__((address_space(3))) void*)l, 16, 0, 0);
}

__device__ __forceinline__ f32x4 mfma16(f16x8 a, f16x8 b, f32x4 c) {
    return __builtin_amdgcn_mfma_f32_16x16x32_f16(a, b, c, 0, 0, 0);
}

#define SCHED0() __builtin_amdgcn_sched_barrier(0)

// ---------------------------------------------------------------------------
// Split X = [input | hidden] (row-major [8192][2048]) into fp16 hi/lo.
// ---------------------------------------------------------------------------
__global__ __launch_bounds__(256) void k_split_x(
    const float* __restrict__ input, const float* __restrict__ hidden,
    unsigned short* __restrict__ xhi, unsigned short* __restrict__ xlo) {
    const int64_t n4 = (int64_t)B_DIM * K1 / 4;
    for (int64_t i = (int64_t)blockIdx.x * blockDim.x + threadIdx.x; i < n4;
         i += (int64_t)gridDim.x * blockDim.x) {
        int64_t e = i * 4;
        int row = (int)(e >> 11);
        int col = (int)(e & 2047);
        const float* src = (col < 1024) ? (input + (int64_t)row * 1024 + col)
                                        : (hidden + (int64_t)row * 1024 + (col - 1024));
        float4 v = *(const float4*)src;
        ushort4 hv, lv;
        hv.x = f2h_bits(v.x); lv.x = f2h_bits(v.x - h2f_bits(hv.x));
        hv.y = f2h_bits(v.y); lv.y = f2h_bits(v.y - h2f_bits(hv.y));
        hv.z = f2h_bits(v.z); lv.z = f2h_bits(v.z - h2f_bits(hv.z));
        hv.w = f2h_bits(v.w); lv.w = f2h_bits(v.w - h2f_bits(hv.w));
        *(ushort4*)(xhi + e) = hv;
        *(ushort4*)(xlo + e) = lv;
    }
}

// ---------------------------------------------------------------------------
// Fused transpose of all 8 gate weights into wuhi[n'=4h+g][k] fp16 (hi only).
// blockIdx.z: 0-3 = W_{f,i,c,o} (koff 0), 4-7 = U_{f,i,c,o} (koff 1024).
// ---------------------------------------------------------------------------
__global__ __launch_bounds__(256) void k_trans_all(
    const float* __restrict__ W_f, const float* __restrict__ W_i,
    const float* __restrict__ W_c, const float* __restrict__ W_o,
    const float* __restrict__ U_f, const float* __restrict__ U_i,
    const float* __restrict__ U_c, const float* __restrict__ U_o,
    unsigned short* __restrict__ wuhi) {
    const int z = blockIdx.z;
    const float* src;
    if      (z == 0) src = W_f;
    else if (z == 1) src = W_i;
    else if (z == 2) src = W_c;
    else if (z == 3) src = W_o;
    else if (z == 4) src = U_f;
    else if (z == 5) src = U_i;
    else if (z == 6) src = U_c;
    else             src = U_o;
    const int ng = z & 3, koff = (z >> 2) * 1024;

    __shared__ float t[64][65];
    const int h0 = blockIdx.x * 64;
    const int k0 = blockIdx.y * 64;
    const int tx = threadIdx.x & 63, ty = threadIdx.x >> 6;
    #pragma unroll
    for (int r = ty; r < 64; r += 4)
        t[r][tx] = src[(int64_t)(k0 + r) * 1024 + h0 + tx];
    __syncthreads();
    #pragma unroll
    for (int r = ty; r < 64; r += 4) {
        float v = t[tx][r];
        int np = (h0 + r) * 4 + ng;
        wuhi[(int64_t)np * 2048 + koff + k0 + tx] = f2h_bits(v);
    }
}

// W_h [1024x1024] (k-major) -> whh[n][k] fp16 hi only.
__global__ __launch_bounds__(256) void k_trans_wh(
    const float* __restrict__ src, unsigned short* __restrict__ whh) {
    __shared__ float t[64][65];
    const int h0 = blockIdx.x * 64;
    const int k0 = blockIdx.y * 64;
    const int tx = threadIdx.x & 63, ty = threadIdx.x >> 6;
    #pragma unroll
    for (int r = ty; r < 64; r += 4)
        t[r][tx] = src[(int64_t)(k0 + r) * 1024 + h0 + tx];
    __syncthreads();
    #pragma unroll
    for (int r = ty; r < 64; r += 4)
        whh[(int64_t)(h0 + r) * 1024 + k0 + tx] = f2h_bits(t[tx][r]);
}

// bias4[n'] = b_g[h], n' = 4h+g
__global__ __launch_bounds__(256) void k_pack_bias(
    const float* __restrict__ bf_, const float* __restrict__ bi_,
    const float* __restrict__ bc_, const float* __restrict__ bo_,
    float* __restrict__ bias4) {
    int n = blockIdx.x * 256 + threadIdx.x;
    if (n < 4096) {
        int g = n & 3, h = n >> 2;
        const float* p = (g == 0) ? bf_ : (g == 1) ? bi_ : (g == 2) ? bc_ : bo_;
        bias4[n] = p[h];
    }
}

// ---------------------------------------------------------------------------
// GATE GEMM: fp16 2-product, 256x256 tile, BK=32, 8 waves (2M x 4N), 16x16x32.
// A LDS rows: 128B = [hi 4x16B | lo 4x16B], slot ^ (row&7) swizzle (R2-proven,
// 0 conflicts).  B LDS rows: 64B hi-only, slot = q ^ ((row>>1)&3) (2-way=free).
// 4 phases/K-tile: {reads; 2 stage calls; barrier+lgkm0; 16 MFMA; barrier};
// counted vmcnt(4) at phase 3 (6 staging calls/tile).  Fused LSTM epilogue.
// ---------------------------------------------------------------------------
__global__ __launch_bounds__(512, 2) void k_gate_gemm(
    const char* __restrict__ Ahi, const char* __restrict__ Alo,
    const char* __restrict__ Bh,
    const float* __restrict__ bias,
    const float* __restrict__ cell,
    float* __restrict__ out0,
    _Float16* __restrict__ hhi, _Float16* __restrict__ hlo) {
    extern __shared__ char smem[];  // 2 * BUF

    const int tid  = threadIdx.x;
    const int lane = tid & 63;
    const int w    = tid >> 6;           // wave 0..7
    const int wr   = (w >> 2) * 128;     // wave M offset
    const int wc   = (w & 3) * 64;       // wave N offset
    const int fr   = lane & 15;
    const int q    = lane >> 4;
    const int sw   = lane & 7;

    // XCD-aware swizzle: 512 blocks, 512%8==0
    const int bid = blockIdx.x;
    const int swz = (bid & 7) * 64 + (bid >> 3);
    const int m0  = (swz >> 4) * 256;
    const int n0  = (swz & 15) * 256;

    f32x4 acc[8][4];
    #pragma unroll
    for (int i = 0; i < 8; i++)
        #pragma unroll
        for (int j = 0; j < 4; j++) acc[i][j] = (f32x4){0.f, 0.f, 0.f, 0.f};

    // --- staging sources (global side carries the swizzle; linear LDS dest) ---
    const int sr = tid >> 3;               // A: row within 64-row chunk
    const int s2 = (tid & 7) ^ (sr & 7);   // A: logical slot (part*4 + kchunk)
    const char* As = ((s2 < 4) ? Ahi : Alo)
                     + (int64_t)(m0 + sr) * 4096 + (s2 & 3) * 16;
    const int brow = tid >> 2;             // B: row within 128-row chunk
    const int bg   = (tid & 3) ^ ((tid >> 3) & 3);  // B: k-chunk for this slot
    const char* Bs = Bh + (int64_t)(n0 + brow) * 4096 + bg * 16;
    const int ldsOff = tid * 16;

    auto SA = [&](int buf, int chunk, int t) {
        gload_lds16(As + (int64_t)chunk * 64 * 4096 + t * 64,
                    smem + buf * BUF + chunk * 8192 + ldsOff);
    };
    auto SB = [&](int buf, int chunk, int t) {
        gload_lds16(Bs + (int64_t)chunk * 128 * 4096 + t * 64,
                    smem + buf * BUF + 32768 + chunk * 8192 + ldsOff);
    };

    // --- ds_read side swizzles ---
    const unsigned hiSlot = (unsigned)((q ^ sw) << 4);
    const unsigned loSlot = (unsigned)(((q + 4) ^ sw) << 4);
    const unsigned bSlot  = (unsigned)((q ^ ((fr >> 1) & 3)) << 4);

    // ---- prologue: tile0 fully (6 calls); tile1 B0,B1,A0,A2 (4 calls) ----
    SA(0, 0, 0); SA(0, 1, 0); SA(0, 2, 0); SA(0, 3, 0);
    SB(0, 0, 0); SB(0, 1, 0);
    SB(1, 0, 1); SB(1, 1, 1);
    SA(1, 0, 1); SA(1, 2, 1);
    asm volatile("s_waitcnt vmcnt(4)" ::: "memory");
    SCHED0();
    __builtin_amdgcn_s_barrier();
    SCHED0();

#define PRE_BAR()                                                   \
    SCHED0();                                                       \
    __builtin_amdgcn_s_barrier();                                   \
    asm volatile("s_waitcnt lgkmcnt(0)" ::: "memory");              \
    SCHED0();

#define POST_BAR()                                                  \
    SCHED0();                                                       \
    __builtin_amdgcn_s_barrier();                                   \
    SCHED0();

#define READ_A(mi, ah, al)                                          \
    {                                                               \
        const char* rp_ = sA + (wr + (mi) * 16 + fr) * 128;         \
        ah = *(const f16x8*)(rp_ + hiSlot);                         \
        al = *(const f16x8*)(rp_ + loSlot);                         \
    }

// 16 MFMAs: hi-products then lo-products (same-acc dep distance 8)
#define MFMA_PAIR(mA, mB)                                           \
    __builtin_amdgcn_s_setprio(1);                                  \
    _Pragma("unroll")                                               \
    for (int ni = 0; ni < 4; ni++) {                                \
        acc[mA][ni] = mfma16(ah0, bh[ni], acc[mA][ni]);             \
        acc[mB][ni] = mfma16(ah1, bh[ni], acc[mB][ni]);             \
    }                                                               \
    _Pragma("unroll")                                               \
    for (int ni = 0; ni < 4; ni++) {                                \
        acc[mA][ni] = mfma16(al0, bh[ni], acc[mA][ni]);             \
        acc[mB][ni] = mfma16(al1, bh[ni], acc[mB][ni]);             \
    }                                                               \
    __builtin_amdgcn_s_setprio(0);

    #pragma unroll 2
    for (int t = 0; t < NT; ++t) {
        const int cc = t & 1;
        const char* sA = smem + cc * BUF;
        const char* sB = sA + 32768;

        f16x8 bh[4];
        f16x8 ah0, al0, ah1, al1;

        // ---- phase 0: read B(all hi) + A(mi0,1); stage A1/A3(t+1) ----
        #pragma unroll
        for (int ni = 0; ni < 4; ni++)
            bh[ni] = *(const f16x8*)(sB + (wc + ni * 16 + fr) * 64 + bSlot);
        READ_A(0, ah0, al0);
        READ_A(1, ah1, al1);
        if (t < NT - 1) { SA(cc ^ 1, 1, t + 1); SA(cc ^ 1, 3, t + 1); }
        PRE_BAR();
        MFMA_PAIR(0, 1);
        POST_BAR();

        // ---- phase 1: read A(mi2,3); stage B0/B1(t+2) ----
        READ_A(2, ah0, al0);
        READ_A(3, ah1, al1);
        if (t < NT - 2) { SB(cc, 0, t + 2); SB(cc, 1, t + 2); }
        PRE_BAR();
        MFMA_PAIR(2, 3);
        POST_BAR();

        // ---- phase 2: read A(mi4,5); stage A0/A2(t+2) ----
        READ_A(4, ah0, al0);
        READ_A(5, ah1, al1);
        if (t < NT - 2) { SA(cc, 0, t + 2); SA(cc, 2, t + 2); }
        PRE_BAR();
        MFMA_PAIR(4, 5);
        POST_BAR();

        // ---- phase 3: read A(mi6,7); MFMA; counted vmcnt ----
        READ_A(6, ah0, al0);
        READ_A(7, ah1, al1);
        PRE_BAR();
        MFMA_PAIR(6, 7);
        SCHED0();
        if (t < NT - 2) {
            asm volatile("s_waitcnt vmcnt(4)" ::: "memory");
        } else if (t == NT - 2) {
            asm volatile("s_waitcnt vmcnt(0)" ::: "memory");
        }
        POST_BAR();
    }

#undef PRE_BAR
#undef POST_BAR
#undef READ_A
#undef MFMA_PAIR

    // ---- fused LSTM epilogue (16x16 C layout: col=lane&15, row=q*4+j) ----
    const int lb = lane & ~3;  // quad lanes lb..lb+3 = gates f,i,c,o of one h
    const int64_t OFF_H = (int64_t)B_DIM * H_DIM;
    const int64_t OFF_C = (int64_t)2 * B_DIM * H_DIM;
    const int g = lane & 3;
    #pragma unroll
    for (int mi = 0; mi < 8; mi++)
        #pragma unroll
        for (int ni = 0; ni < 4; ni++) {
            int col = n0 + wc + ni * 16 + fr;  // n' = 4h+g
            int h = col >> 2;
            float bb = bias[col];
            int rowb = m0 + wr + mi * 16 + q * 4;
            #pragma unroll
            for (int j = 0; j < 4; j++) {
                float v = acc[mi][ni][j] + bb;
                float a = (g == 2) ? tanhf(v) : 1.0f / (1.0f + expf(-v));
                float fg = __shfl(a, lb + 0, 64);
                float ig = __shfl(a, lb + 1, 64);
                float ct = __shfl(a, lb + 2, 64);
                float og = __shfl(a, lb + 3, 64);
                int row = rowb + j;
                int64_t o = (int64_t)row * H_DIM + h;
                float cn = fg * cell[o] + ig * ct;
                float hn = og * tanhf(cn);
                if (g == 0) {
                    out0[OFF_C + o] = cn;
                } else if (g == 1) {
                    out0[OFF_H + o] = hn;
                } else if (g == 2) {
                    hhi[o] = (_Float16)hn;
                } else {
                    _Float16 hh = (_Float16)hn;
                    hlo[o] = (_Float16)(hn - (float)hh);
                }
            }
        }
}

// ---------------------------------------------------------------------------
// LOGITS GEMM: fp16 2-product, 128x128 tile, BK=32, 4 waves (m97 structure).
// A = h hi/lo fp16 [8192][1024]; B = W_h^T fp16 hi-only [1024][1024].
// ---------------------------------------------------------------------------
__global__ __launch_bounds__(256, 2) void k_gemm128(
    const char* __restrict__ Ahi, const char* __restrict__ Alo,
    const char* __restrict__ Bh,
    const float* __restrict__ bias,
    float* __restrict__ out0) {
    __shared__ char smem[24576];  // A 16KB | B 8KB

    const int tid  = threadIdx.x;
    const int lane = tid & 63;
    const int w    = tid >> 6;
    const int wr   = (w >> 1) * 64;
    const int wc   = (w & 1) * 64;
    const int m0   = blockIdx.y * 128;
    const int n0   = blockIdx.x * 128;
    const int fr   = lane & 15;
    const int q    = lane >> 4;
    const int sw   = lane & 7;

    f32x4 acc[4][4];
    #pragma unroll
    for (int i = 0; i < 4; i++)
        #pragma unroll
        for (int j = 0; j < 4; j++) acc[i][j] = (f32x4){0.f, 0.f, 0.f, 0.f};

    const int sr = tid >> 3;               // 0..31
    const int s2 = (tid & 7) ^ (sr & 7);
    const char* As = ((s2 < 4) ? Ahi : Alo)
                     + (int64_t)(m0 + sr) * 2048 + (s2 & 3) * 16;
    const int brow = tid >> 2;             // 0..63
    const int bg   = (tid & 3) ^ ((tid >> 3) & 3);
    const char* Bs = Bh + (int64_t)(n0 + brow) * 2048 + bg * 16;

    const unsigned hiSlot = (unsigned)((q ^ sw) << 4);
    const unsigned loSlot = (unsigned)(((q + 4) ^ sw) << 4);
    const unsigned bSlot  = (unsigned)((q ^ ((fr >> 1) & 3)) << 4);

    for (int t = 0; t < 32; ++t) {   // K=1024, BK=32
        __syncthreads();
        #pragma unroll
        for (int i = 0; i < 4; i++)
            gload_lds16(As + (int64_t)i * 32 * 2048 + t * 64,
                        smem + i * 4096 + tid * 16);
        #pragma unroll
        for (int i = 0; i < 2; i++)
            gload_lds16(Bs + (int64_t)i * 64 * 2048 + t * 64,
                        smem + 16384 + i * 4096 + tid * 16);
        __syncthreads();

        f16x8 ah[4], al[4], bh[4];
        #pragma unroll
        for (int mi = 0; mi < 4; mi++) {
            const char* rp = smem + (wr + mi * 16 + fr) * 128;
            ah[mi] = *(const f16x8*)(rp + hiSlot);
            al[mi] = *(const f16x8*)(rp + loSlot);
        }
        #pragma unroll
        for (int ni = 0; ni < 4; ni++)
            bh[ni] = *(const f16x8*)(smem + 16384 + (wc + ni * 16 + fr) * 64 + bSlot);

        #pragma unroll
        for (int ni = 0; ni < 4; ni++)
            #pragma unroll
            for (int mi = 0; mi < 4; mi++)
                acc[mi][ni] = mfma16(ah[mi], bh[ni], acc[mi][ni]);
        #pragma unroll
        for (int ni = 0; ni < 4; ni++)
            #pragma unroll
            for (int mi = 0; mi < 4; mi++)
                acc[mi][ni] = mfma16(al[mi], bh[ni], acc[mi][ni]);
    }

    #pragma unroll
    for (int mi = 0; mi < 4; mi++)
        #pragma unroll
        for (int ni = 0; ni < 4; ni++) {
            int col = n0 + wc + ni * 16 + fr;
            int rowb = m0 + wr + mi * 16 + q * 4;
            float bb = bias[col];
            #pragma unroll
            for (int j = 0; j < 4; j++)
                out0[(int64_t)(rowb + j) * 1024 + col] = acc[mi][ni][j] + bb;
        }
}

// ---------------------------------------------------------------------------
// Row-wise log_softmax over [8192][1024]: one block per row.
// ---------------------------------------------------------------------------
__global__ __launch_bounds__(256) void k_logsoftmax(
    const float* __restrict__ logits, float* __restrict__ out) {
    const int row = blockIdx.x;
    const int t = threadIdx.x;
    const float* x = logits + (int64_t)row * 1024;
    float4 v = *(const float4*)(x + t * 4);

    float m = fmaxf(fmaxf(v.x, v.y), fmaxf(v.z, v.w));
    #pragma unroll
    for (int off = 1; off < 64; off <<= 1) m = fmaxf(m, __shfl_xor(m, off, 64));
    __shared__ float sm[4];
    __shared__ float ssum[4];
    int ln = t & 63, wv = t >> 6;
    if (ln == 0) sm[wv] = m;
    __syncthreads();
    m = fmaxf(fmaxf(sm[0], sm[1]), fmaxf(sm[2], sm[3]));

    float s = expf(v.x - m) + expf(v.y - m) + expf(v.z - m) + expf(v.w - m);
    #pragma unroll
    for (int off = 1; off < 64; off <<= 1) s += __shfl_xor(s, off, 64);
    if (ln == 0) ssum[wv] = s;
    __syncthreads();
    s = ssum[0] + ssum[1] + ssum[2] + ssum[3];

    float lse = m + logf(s);
    float4 o;
    o.x = v.x - lse; o.y = v.y - lse; o.z = v.z - lse; o.w = v.w - lse;
    *(float4*)(out + (int64_t)row * 1024 + t * 4) = o;
}

// ---------------------------------------------------------------------------
extern "C" void kernel_launch(void* const* d_in, const int* in_sizes, int n_in,
                              void* d_out, int out_size, void* d_ws, size_t ws_size,
                              hipStream_t stream) {
    const float* input  = (const float*)d_in[0];
    const float* hidden = (const float*)d_in[1];
    const float* cell   = (const float*)d_in[2];
    const float* W_f = (const float*)d_in[3];
    const float* U_f = (const float*)d_in[4];
    const float* b_f = (const float*)d_in[5];
    const float* W_i = (const float*)d_in[6];
    const float* U_i = (const float*)d_in[7];
    const float* b_i = (const float*)d_in[8];
    const float* W_c = (const float*)d_in[9];
    const float* U_c = (const float*)d_in[10];
    const float* b_c = (const float*)d_in[11];
    const float* W_o = (const float*)d_in[12];
    const float* U_o = (const float*)d_in[13];
    const float* b_o = (const float*)d_in[14];
    const float* W_h = (const float*)d_in[15];
    const float* b_h = (const float*)d_in[16];
    float* out = (float*)d_out;

    char* ws = (char*)d_ws;
    unsigned short* xhi  = (unsigned short*)(ws);               // 32 MB
    unsigned short* xlo  = (unsigned short*)(ws + 33554432);    // 32 MB
    unsigned short* wuhi = (unsigned short*)(ws + 67108864);    // 16 MB
    _Float16*       hhi  = (_Float16*)(ws + 83886080);          // 16 MB
    _Float16*       hlo  = (_Float16*)(ws + 100663296);         // 16 MB
    unsigned short* whh  = (unsigned short*)(ws + 117440512);   // 2 MB
    float*          bias4 = (float*)(ws + 119537664);           // 16 KB
    float*          logits = (float*)(ws);                      // aliases X
    if (ws_size < (size_t)119554048) return;

    hipFuncSetAttribute((const void*)k_gate_gemm,
                        hipFuncAttributeMaxDynamicSharedMemorySize, 2 * BUF);

    k_split_x<<<2048, 256, 0, stream>>>(input, hidden, xhi, xlo);
    k_trans_all<<<dim3(16, 16, 8), 256, 0, stream>>>(
        W_f, W_i, W_c, W_o, U_f, U_i, U_c, U_o, wuhi);
    k_trans_wh<<<dim3(16, 16), 256, 0, stream>>>(W_h, whh);
    k_pack_bias<<<16, 256, 0, stream>>>(b_f, b_i, b_c, b_o, bias4);

    // gates GEMM + fused LSTM epilogue: M=8192, N'=4096, K=2048, 512 blocks
    k_gate_gemm<<<512, 512, 2 * BUF, stream>>>(
        (const char*)xhi, (const char*)xlo, (const char*)wuhi,
        bias4, cell, out, hhi, hlo);

    // logits GEMM: M=8192, N=1024, K=1024
    k_gemm128<<<dim3(8, 64), 256, 0, stream>>>(
        (const char*)hhi, (const char*)hlo, (const char*)whh, b_h, logits);

    k_logsoftmax<<<8192, 256, 0, stream>>>(logits, out);
}

// Round 11
// 486.898 us; speedup vs baseline: 2.0847x; 1.0220x over previous
//
#include <hip/hip_runtime.h>
#include <hip/hip_bf16.h>
#include <cstdint>

// ---------------------------------------------------------------------------
// LSTM cell fused forward on MI355X (gfx950).
//   gates = [input|hidden] @ [W;U] + b  -- fp32 via fp16 2-product emulation:
//     x*W ~= x_hi*W_hi + x_lo*W_hi   (A to ~22 bits, W fp16-quantized)
//   gate GEMM: m97-structure 128^2 / BK=32 / 4-wave / single-buffer LDS
//              (24KB -> 2-3 blocks/CU; inter-block TLP hides staging)
//   elementwise LSTM epilogue fused; logits = h @ W_h + b_h (same 2-product);
//   log_softmax row-wise.
// ---------------------------------------------------------------------------

#define B_DIM   8192
#define K1      2048
#define H_DIM   1024
#define NT      64        // K1/32

typedef __attribute__((ext_vector_type(8))) _Float16 f16x8;
typedef __attribute__((ext_vector_type(4))) float    f32x4;

__device__ __forceinline__ unsigned short f2h_bits(float x) {
    _Float16 h = (_Float16)x;
    return __builtin_bit_cast(unsigned short, h);
}
__device__ __forceinline__ float h2f_bits(unsigned short b) {
    return (float)__builtin_bit_cast(_Float16, b);
}

__device__ __forceinline__ void gload_lds16(const void* g, void* l) {
    __builtin_amdgcn_global_load_lds(
        (const __attribute__((address_space(1))) void*)g,
        (__attribute__((address_space(3))) void*)l, 16, 0, 0);
}

__device__ __forceinline__ f32x4 mfma16(f16x8 a, f16x8 b, f32x4 c) {
    return __builtin_amdgcn_mfma_f32_16x16x32_f16(a, b, c, 0, 0, 0);
}

// ---------------------------------------------------------------------------
// Split X = [input | hidden] (row-major [8192][2048]) into fp16 hi/lo.
// ---------------------------------------------------------------------------
__global__ __launch_bounds__(256) void k_split_x(
    const float* __restrict__ input, const float* __restrict__ hidden,
    unsigned short* __restrict__ xhi, unsigned short* __restrict__ xlo) {
    const int64_t n4 = (int64_t)B_DIM * K1 / 4;
    for (int64_t i = (int64_t)blockIdx.x * blockDim.x + threadIdx.x; i < n4;
         i += (int64_t)gridDim.x * blockDim.x) {
        int64_t e = i * 4;
        int row = (int)(e >> 11);
        int col = (int)(e & 2047);
        const float* src = (col < 1024) ? (input + (int64_t)row * 1024 + col)
                                        : (hidden + (int64_t)row * 1024 + (col - 1024));
        float4 v = *(const float4*)src;
        ushort4 hv, lv;
        hv.x = f2h_bits(v.x); lv.x = f2h_bits(v.x - h2f_bits(hv.x));
        hv.y = f2h_bits(v.y); lv.y = f2h_bits(v.y - h2f_bits(hv.y));
        hv.z = f2h_bits(v.z); lv.z = f2h_bits(v.z - h2f_bits(hv.z));
        hv.w = f2h_bits(v.w); lv.w = f2h_bits(v.w - h2f_bits(hv.w));
        *(ushort4*)(xhi + e) = hv;
        *(ushort4*)(xlo + e) = lv;
    }
}

// ---------------------------------------------------------------------------
// Fused transpose of all 8 gate weights into wuhi[n'=4h+g][k] fp16 (hi only).
// blockIdx.z: 0-3 = W_{f,i,c,o} (koff 0), 4-7 = U_{f,i,c,o} (koff 1024).
// ---------------------------------------------------------------------------
__global__ __launch_bounds__(256) void k_trans_all(
    const float* __restrict__ W_f, const float* __restrict__ W_i,
    const float* __restrict__ W_c, const float* __restrict__ W_o,
    const float* __restrict__ U_f, const float* __restrict__ U_i,
    const float* __restrict__ U_c, const float* __restrict__ U_o,
    unsigned short* __restrict__ wuhi) {
    const int z = blockIdx.z;
    const float* src;
    if      (z == 0) src = W_f;
    else if (z == 1) src = W_i;
    else if (z == 2) src = W_c;
    else if (z == 3) src = W_o;
    else if (z == 4) src = U_f;
    else if (z == 5) src = U_i;
    else if (z == 6) src = U_c;
    else             src = U_o;
    const int ng = z & 3, koff = (z >> 2) * 1024;

    __shared__ float t[64][65];
    const int h0 = blockIdx.x * 64;
    const int k0 = blockIdx.y * 64;
    const int tx = threadIdx.x & 63, ty = threadIdx.x >> 6;
    #pragma unroll
    for (int r = ty; r < 64; r += 4)
        t[r][tx] = src[(int64_t)(k0 + r) * 1024 + h0 + tx];
    __syncthreads();
    #pragma unroll
    for (int r = ty; r < 64; r += 4) {
        float v = t[tx][r];
        int np = (h0 + r) * 4 + ng;
        wuhi[(int64_t)np * 2048 + koff + k0 + tx] = f2h_bits(v);
    }
}

// W_h [1024x1024] (k-major) -> whh[n][k] fp16 hi only.
__global__ __launch_bounds__(256) void k_trans_wh(
    const float* __restrict__ src, unsigned short* __restrict__ whh) {
    __shared__ float t[64][65];
    const int h0 = blockIdx.x * 64;
    const int k0 = blockIdx.y * 64;
    const int tx = threadIdx.x & 63, ty = threadIdx.x >> 6;
    #pragma unroll
    for (int r = ty; r < 64; r += 4)
        t[r][tx] = src[(int64_t)(k0 + r) * 1024 + h0 + tx];
    __syncthreads();
    #pragma unroll
    for (int r = ty; r < 64; r += 4)
        whh[(int64_t)(h0 + r) * 1024 + k0 + tx] = f2h_bits(t[tx][r]);
}

// bias4[n'] = b_g[h], n' = 4h+g
__global__ __launch_bounds__(256) void k_pack_bias(
    const float* __restrict__ bf_, const float* __restrict__ bi_,
    const float* __restrict__ bc_, const float* __restrict__ bo_,
    float* __restrict__ bias4) {
    int n = blockIdx.x * 256 + threadIdx.x;
    if (n < 4096) {
        int g = n & 3, h = n >> 2;
        const float* p = (g == 0) ? bf_ : (g == 1) ? bi_ : (g == 2) ? bc_ : bo_;
        bias4[n] = p[h];
    }
}

// ---------------------------------------------------------------------------
// GATE GEMM: fp16 2-product, m97 structure.  128x128 tile, BK=32, 4 waves
// (2M x 2N, 64x64 each), 16x16x32 MFMA, single-buffered 24KB LDS.
// A LDS rows: 128B = [hi 4x16B | lo 4x16B], slot ^ (row&7) swizzle (proven 0
// conflicts).  B LDS rows: 64B hi-only, slot = q ^ ((row>>1)&3).
// Loop: {sync; 6 gload_lds; sync; 12 ds_read; 32 MFMA} -- compiler inserts
// waits; 2-3 blocks/CU give inter-block overlap (m114).  Fused LSTM epilogue.
// ---------------------------------------------------------------------------
__global__ __launch_bounds__(256, 2) void k_gate_gemm(
    const char* __restrict__ Ahi, const char* __restrict__ Alo,
    const char* __restrict__ Bh,
    const float* __restrict__ bias,
    const float* __restrict__ cell,
    float* __restrict__ out0,
    _Float16* __restrict__ hhi, _Float16* __restrict__ hlo) {
    __shared__ char smem[24576];  // A 16KB | B 8KB

    const int tid  = threadIdx.x;
    const int lane = tid & 63;
    const int w    = tid >> 6;           // wave 0..3
    const int wr   = (w >> 1) * 64;      // wave M offset
    const int wc   = (w & 1) * 64;       // wave N offset
    const int fr   = lane & 15;
    const int q    = lane >> 4;
    const int sw   = lane & 7;
    const int m0   = blockIdx.y * 128;
    const int n0   = blockIdx.x * 128;

    f32x4 acc[4][4];
    #pragma unroll
    for (int i = 0; i < 4; i++)
        #pragma unroll
        for (int j = 0; j < 4; j++) acc[i][j] = (f32x4){0.f, 0.f, 0.f, 0.f};

    // --- staging sources (global side carries the swizzle; linear LDS dest) ---
    const int sr = tid >> 3;               // A: row within 32-row chunk (0..31)
    const int s2 = (tid & 7) ^ (sr & 7);   // A: logical slot (part*4 + kchunk)
    const char* As = ((s2 < 4) ? Ahi : Alo)
                     + (int64_t)(m0 + sr) * 4096 + (s2 & 3) * 16;
    const int brow = tid >> 2;             // B: row within 64-row chunk (0..63)
    const int bg   = (tid & 3) ^ ((tid >> 3) & 3);  // B: k-chunk for this slot
    const char* Bs = Bh + (int64_t)(n0 + brow) * 4096 + bg * 16;

    // --- ds_read side swizzles ---
    const unsigned hiSlot = (unsigned)((q ^ sw) << 4);
    const unsigned loSlot = (unsigned)(((q + 4) ^ sw) << 4);
    const unsigned bSlot  = (unsigned)((q ^ ((fr >> 1) & 3)) << 4);

    for (int t = 0; t < NT; ++t) {
        __syncthreads();   // previous-iteration LDS readers done
        #pragma unroll
        for (int i = 0; i < 4; i++)
            gload_lds16(As + (int64_t)i * 32 * 4096 + t * 64,
                        smem + i * 4096 + tid * 16);
        #pragma unroll
        for (int i = 0; i < 2; i++)
            gload_lds16(Bs + (int64_t)i * 64 * 4096 + t * 64,
                        smem + 16384 + i * 4096 + tid * 16);
        __syncthreads();   // loads landed (compiler drains vmcnt)

        f16x8 ah[4], al[4], bh[4];
        #pragma unroll
        for (int mi = 0; mi < 4; mi++) {
            const char* rp = smem + (wr + mi * 16 + fr) * 128;
            ah[mi] = *(const f16x8*)(rp + hiSlot);
            al[mi] = *(const f16x8*)(rp + loSlot);
        }
        #pragma unroll
        for (int ni = 0; ni < 4; ni++)
            bh[ni] = *(const f16x8*)(smem + 16384 + (wc + ni * 16 + fr) * 64 + bSlot);

        #pragma unroll
        for (int ni = 0; ni < 4; ni++)
            #pragma unroll
            for (int mi = 0; mi < 4; mi++)
                acc[mi][ni] = mfma16(ah[mi], bh[ni], acc[mi][ni]);
        #pragma unroll
        for (int ni = 0; ni < 4; ni++)
            #pragma unroll
            for (int mi = 0; mi < 4; mi++)
                acc[mi][ni] = mfma16(al[mi], bh[ni], acc[mi][ni]);
    }

    // ---- fused LSTM epilogue (16x16 C layout: col=lane&15, row=q*4+j) ----
    const int lb = lane & ~3;  // quad lanes lb..lb+3 = gates f,i,c,o of one h
    const int64_t OFF_H = (int64_t)B_DIM * H_DIM;
    const int64_t OFF_C = (int64_t)2 * B_DIM * H_DIM;
    const int g = lane & 3;
    #pragma unroll
    for (int mi = 0; mi < 4; mi++)
        #pragma unroll
        for (int ni = 0; ni < 4; ni++) {
            int col = n0 + wc + ni * 16 + fr;  // n' = 4h+g
            int h = col >> 2;
            float bb = bias[col];
            int rowb = m0 + wr + mi * 16 + q * 4;
            #pragma unroll
            for (int j = 0; j < 4; j++) {
                float v = acc[mi][ni][j] + bb;
                float a = (g == 2) ? tanhf(v) : 1.0f / (1.0f + expf(-v));
                float fg = __shfl(a, lb + 0, 64);
                float ig = __shfl(a, lb + 1, 64);
                float ct = __shfl(a, lb + 2, 64);
                float og = __shfl(a, lb + 3, 64);
                int row = rowb + j;
                int64_t o = (int64_t)row * H_DIM + h;
                float cn = fg * cell[o] + ig * ct;
                float hn = og * tanhf(cn);
                if (g == 0) {
                    out0[OFF_C + o] = cn;
                } else if (g == 1) {
                    out0[OFF_H + o] = hn;
                } else if (g == 2) {
                    hhi[o] = (_Float16)hn;
                } else {
                    _Float16 hh = (_Float16)hn;
                    hlo[o] = (_Float16)(hn - (float)hh);
                }
            }
        }
}

// ---------------------------------------------------------------------------
// LOGITS GEMM: fp16 2-product, 128x128 tile, BK=32, 4 waves (m97 structure).
// A = h hi/lo fp16 [8192][1024]; B = W_h^T fp16 hi-only [1024][1024].
// ---------------------------------------------------------------------------
__global__ __launch_bounds__(256, 2) void k_gemm128(
    const char* __restrict__ Ahi, const char* __restrict__ Alo,
    const char* __restrict__ Bh,
    const float* __restrict__ bias,
    float* __restrict__ out0) {
    __shared__ char smem[24576];  // A 16KB | B 8KB

    const int tid  = threadIdx.x;
    const int lane = tid & 63;
    const int w    = tid >> 6;
    const int wr   = (w >> 1) * 64;
    const int wc   = (w & 1) * 64;
    const int m0   = blockIdx.y * 128;
    const int n0   = blockIdx.x * 128;
    const int fr   = lane & 15;
    const int q    = lane >> 4;
    const int sw   = lane & 7;

    f32x4 acc[4][4];
    #pragma unroll
    for (int i = 0; i < 4; i++)
        #pragma unroll
        for (int j = 0; j < 4; j++) acc[i][j] = (f32x4){0.f, 0.f, 0.f, 0.f};

    const int sr = tid >> 3;               // 0..31
    const int s2 = (tid & 7) ^ (sr & 7);
    const char* As = ((s2 < 4) ? Ahi : Alo)
                     + (int64_t)(m0 + sr) * 2048 + (s2 & 3) * 16;
    const int brow = tid >> 2;             // 0..63
    const int bg   = (tid & 3) ^ ((tid >> 3) & 3);
    const char* Bs = Bh + (int64_t)(n0 + brow) * 2048 + bg * 16;

    const unsigned hiSlot = (unsigned)((q ^ sw) << 4);
    const unsigned loSlot = (unsigned)(((q + 4) ^ sw) << 4);
    const unsigned bSlot  = (unsigned)((q ^ ((fr >> 1) & 3)) << 4);

    for (int t = 0; t < 32; ++t) {   // K=1024, BK=32
        __syncthreads();
        #pragma unroll
        for (int i = 0; i < 4; i++)
            gload_lds16(As + (int64_t)i * 32 * 2048 + t * 64,
                        smem + i * 4096 + tid * 16);
        #pragma unroll
        for (int i = 0; i < 2; i++)
            gload_lds16(Bs + (int64_t)i * 64 * 2048 + t * 64,
                        smem + 16384 + i * 4096 + tid * 16);
        __syncthreads();

        f16x8 ah[4], al[4], bh[4];
        #pragma unroll
        for (int mi = 0; mi < 4; mi++) {
            const char* rp = smem + (wr + mi * 16 + fr) * 128;
            ah[mi] = *(const f16x8*)(rp + hiSlot);
            al[mi] = *(const f16x8*)(rp + loSlot);
        }
        #pragma unroll
        for (int ni = 0; ni < 4; ni++)
            bh[ni] = *(const f16x8*)(smem + 16384 + (wc + ni * 16 + fr) * 64 + bSlot);

        #pragma unroll
        for (int ni = 0; ni < 4; ni++)
            #pragma unroll
            for (int mi = 0; mi < 4; mi++)
                acc[mi][ni] = mfma16(ah[mi], bh[ni], acc[mi][ni]);
        #pragma unroll
        for (int ni = 0; ni < 4; ni++)
            #pragma unroll
            for (int mi = 0; mi < 4; mi++)
                acc[mi][ni] = mfma16(al[mi], bh[ni], acc[mi][ni]);
    }

    #pragma unroll
    for (int mi = 0; mi < 4; mi++)
        #pragma unroll
        for (int ni = 0; ni < 4; ni++) {
            int col = n0 + wc + ni * 16 + fr;
            int rowb = m0 + wr + mi * 16 + q * 4;
            float bb = bias[col];
            #pragma unroll
            for (int j = 0; j < 4; j++)
                out0[(int64_t)(rowb + j) * 1024 + col] = acc[mi][ni][j] + bb;
        }
}

// ---------------------------------------------------------------------------
// Row-wise log_softmax over [8192][1024]: one block per row.
// ---------------------------------------------------------------------------
__global__ __launch_bounds__(256) void k_logsoftmax(
    const float* __restrict__ logits, float* __restrict__ out) {
    const int row = blockIdx.x;
    const int t = threadIdx.x;
    const float* x = logits + (int64_t)row * 1024;
    float4 v = *(const float4*)(x + t * 4);

    float m = fmaxf(fmaxf(v.x, v.y), fmaxf(v.z, v.w));
    #pragma unroll
    for (int off = 1; off < 64; off <<= 1) m = fmaxf(m, __shfl_xor(m, off, 64));
    __shared__ float sm[4];
    __shared__ float ssum[4];
    int ln = t & 63, wv = t >> 6;
    if (ln == 0) sm[wv] = m;
    __syncthreads();
    m = fmaxf(fmaxf(sm[0], sm[1]), fmaxf(sm[2], sm[3]));

    float s = expf(v.x - m) + expf(v.y - m) + expf(v.z - m) + expf(v.w - m);
    #pragma unroll
    for (int off = 1; off < 64; off <<= 1) s += __shfl_xor(s, off, 64);
    if (ln == 0) ssum[wv] = s;
    __syncthreads();
    s = ssum[0] + ssum[1] + ssum[2] + ssum[3];

    float lse = m + logf(s);
    float4 o;
    o.x = v.x - lse; o.y = v.y - lse; o.z = v.z - lse; o.w = v.w - lse;
    *(float4*)(out + (int64_t)row * 1024 + t * 4) = o;
}

// ---------------------------------------------------------------------------
extern "C" void kernel_launch(void* const* d_in, const int* in_sizes, int n_in,
                              void* d_out, int out_size, void* d_ws, size_t ws_size,
                              hipStream_t stream) {
    const float* input  = (const float*)d_in[0];
    const float* hidden = (const float*)d_in[1];
    const float* cell   = (const float*)d_in[2];
    const float* W_f = (const float*)d_in[3];
    const float* U_f = (const float*)d_in[4];
    const float* b_f = (const float*)d_in[5];
    const float* W_i = (const float*)d_in[6];
    const float* U_i = (const float*)d_in[7];
    const float* b_i = (const float*)d_in[8];
    const float* W_c = (const float*)d_in[9];
    const float* U_c = (const float*)d_in[10];
    const float* b_c = (const float*)d_in[11];
    const float* W_o = (const float*)d_in[12];
    const float* U_o = (const float*)d_in[13];
    const float* b_o = (const float*)d_in[14];
    const float* W_h = (const float*)d_in[15];
    const float* b_h = (const float*)d_in[16];
    float* out = (float*)d_out;

    char* ws = (char*)d_ws;
    unsigned short* xhi  = (unsigned short*)(ws);               // 32 MB
    unsigned short* xlo  = (unsigned short*)(ws + 33554432);    // 32 MB
    unsigned short* wuhi = (unsigned short*)(ws + 67108864);    // 16 MB
    _Float16*       hhi  = (_Float16*)(ws + 83886080);          // 16 MB
    _Float16*       hlo  = (_Float16*)(ws + 100663296);         // 16 MB
    unsigned short* whh  = (unsigned short*)(ws + 117440512);   // 2 MB
    float*          bias4 = (float*)(ws + 119537664);           // 16 KB
    float*          logits = (float*)(ws);                      // aliases X
    if (ws_size < (size_t)119554048) return;

    k_split_x<<<2048, 256, 0, stream>>>(input, hidden, xhi, xlo);
    k_trans_all<<<dim3(16, 16, 8), 256, 0, stream>>>(
        W_f, W_i, W_c, W_o, U_f, U_i, U_c, U_o, wuhi);
    k_trans_wh<<<dim3(16, 16), 256, 0, stream>>>(W_h, whh);
    k_pack_bias<<<16, 256, 0, stream>>>(b_f, b_i, b_c, b_o, bias4);

    // gates GEMM + fused LSTM epilogue: M=8192, N'=4096, K=2048, 2048 blocks
    k_gate_gemm<<<dim3(32, 64), 256, 0, stream>>>(
        (const char*)xhi, (const char*)xlo, (const char*)wuhi,
        bias4, cell, out, hhi, hlo);

    // logits GEMM: M=8192, N=1024, K=1024
    k_gemm128<<<dim3(8, 64), 256, 0, stream>>>(
        (const char*)hhi, (const char*)hlo, (const char*)whh, b_h, logits);

    k_logsoftmax<<<8192, 256, 0, stream>>>(logits, out);
}

// Round 12
// 458.533 us; speedup vs baseline: 2.2137x; 1.0619x over previous
//
#include <hip/hip_runtime.h>
#include <hip/hip_bf16.h>
#include <cstdint>

// ---------------------------------------------------------------------------
// LSTM cell fused forward on MI355X (gfx950).
//   gates = [input|hidden] @ [W;U] + b  -- fp32 via fp16 2-product emulation:
//     x*W ~= x_hi*W_hi + x_lo*W_hi   (A to ~22 bits, W fp16-quantized)
//   gate GEMM: m97-structure 128^2, BK=64 (2 x BK32 subtiles, one drain per
//              64-K), 4 waves, 48KB LDS (3 blocks/CU TLP)
//   elementwise LSTM epilogue fused; logits = h_hi @ W_h + b_h (1-product);
//   log_softmax row-wise.
// ---------------------------------------------------------------------------

#define B_DIM   8192
#define K1      2048
#define H_DIM   1024

typedef __attribute__((ext_vector_type(8))) _Float16 f16x8;
typedef __attribute__((ext_vector_type(4))) float    f32x4;

__device__ __forceinline__ unsigned short f2h_bits(float x) {
    _Float16 h = (_Float16)x;
    return __builtin_bit_cast(unsigned short, h);
}
__device__ __forceinline__ float h2f_bits(unsigned short b) {
    return (float)__builtin_bit_cast(_Float16, b);
}

__device__ __forceinline__ void gload_lds16(const void* g, void* l) {
    __builtin_amdgcn_global_load_lds(
        (const __attribute__((address_space(1))) void*)g,
        (__attribute__((address_space(3))) void*)l, 16, 0, 0);
}

__device__ __forceinline__ f32x4 mfma16(f16x8 a, f16x8 b, f32x4 c) {
    return __builtin_amdgcn_mfma_f32_16x16x32_f16(a, b, c, 0, 0, 0);
}

// ---------------------------------------------------------------------------
// Split X = [input | hidden] (row-major [8192][2048]) into fp16 hi/lo.
// ---------------------------------------------------------------------------
__global__ __launch_bounds__(256) void k_split_x(
    const float* __restrict__ input, const float* __restrict__ hidden,
    unsigned short* __restrict__ xhi, unsigned short* __restrict__ xlo) {
    const int64_t n4 = (int64_t)B_DIM * K1 / 4;
    for (int64_t i = (int64_t)blockIdx.x * blockDim.x + threadIdx.x; i < n4;
         i += (int64_t)gridDim.x * blockDim.x) {
        int64_t e = i * 4;
        int row = (int)(e >> 11);
        int col = (int)(e & 2047);
        const float* src = (col < 1024) ? (input + (int64_t)row * 1024 + col)
                                        : (hidden + (int64_t)row * 1024 + (col - 1024));
        float4 v = *(const float4*)src;
        ushort4 hv, lv;
        hv.x = f2h_bits(v.x); lv.x = f2h_bits(v.x - h2f_bits(hv.x));
        hv.y = f2h_bits(v.y); lv.y = f2h_bits(v.y - h2f_bits(hv.y));
        hv.z = f2h_bits(v.z); lv.z = f2h_bits(v.z - h2f_bits(hv.z));
        hv.w = f2h_bits(v.w); lv.w = f2h_bits(v.w - h2f_bits(hv.w));
        *(ushort4*)(xhi + e) = hv;
        *(ushort4*)(xlo + e) = lv;
    }
}

// ---------------------------------------------------------------------------
// Fused transpose of all 8 gate weights into wuhi[n'=4h+g][k] fp16 (hi only).
// blockIdx.z: 0-3 = W_{f,i,c,o} (koff 0), 4-7 = U_{f,i,c,o} (koff 1024).
// ---------------------------------------------------------------------------
__global__ __launch_bounds__(256) void k_trans_all(
    const float* __restrict__ W_f, const float* __restrict__ W_i,
    const float* __restrict__ W_c, const float* __restrict__ W_o,
    const float* __restrict__ U_f, const float* __restrict__ U_i,
    const float* __restrict__ U_c, const float* __restrict__ U_o,
    unsigned short* __restrict__ wuhi) {
    const int z = blockIdx.z;
    const float* src;
    if      (z == 0) src = W_f;
    else if (z == 1) src = W_i;
    else if (z == 2) src = W_c;
    else if (z == 3) src = W_o;
    else if (z == 4) src = U_f;
    else if (z == 5) src = U_i;
    else if (z == 6) src = U_c;
    else             src = U_o;
    const int ng = z & 3, koff = (z >> 2) * 1024;

    __shared__ float t[64][65];
    const int h0 = blockIdx.x * 64;
    const int k0 = blockIdx.y * 64;
    const int tx = threadIdx.x & 63, ty = threadIdx.x >> 6;
    #pragma unroll
    for (int r = ty; r < 64; r += 4)
        t[r][tx] = src[(int64_t)(k0 + r) * 1024 + h0 + tx];
    __syncthreads();
    #pragma unroll
    for (int r = ty; r < 64; r += 4) {
        float v = t[tx][r];
        int np = (h0 + r) * 4 + ng;
        wuhi[(int64_t)np * 2048 + koff + k0 + tx] = f2h_bits(v);
    }
}

// W_h [1024x1024] (k-major) -> whh[n][k] fp16 hi only.
__global__ __launch_bounds__(256) void k_trans_wh(
    const float* __restrict__ src, unsigned short* __restrict__ whh) {
    __shared__ float t[64][65];
    const int h0 = blockIdx.x * 64;
    const int k0 = blockIdx.y * 64;
    const int tx = threadIdx.x & 63, ty = threadIdx.x >> 6;
    #pragma unroll
    for (int r = ty; r < 64; r += 4)
        t[r][tx] = src[(int64_t)(k0 + r) * 1024 + h0 + tx];
    __syncthreads();
    #pragma unroll
    for (int r = ty; r < 64; r += 4)
        whh[(int64_t)(h0 + r) * 1024 + k0 + tx] = f2h_bits(t[tx][r]);
}

// bias4[n'] = b_g[h], n' = 4h+g
__global__ __launch_bounds__(256) void k_pack_bias(
    const float* __restrict__ bf_, const float* __restrict__ bi_,
    const float* __restrict__ bc_, const float* __restrict__ bo_,
    float* __restrict__ bias4) {
    int n = blockIdx.x * 256 + threadIdx.x;
    if (n < 4096) {
        int g = n & 3, h = n >> 2;
        const float* p = (g == 0) ? bf_ : (g == 1) ? bi_ : (g == 2) ? bc_ : bo_;
        bias4[n] = p[h];
    }
}

// ---------------------------------------------------------------------------
// GATE GEMM: fp16 2-product, m97 structure.  128x128 tile, BK=64 as two BK32
// subtiles, 4 waves (2M x 2N, 64x64 each), 16x16x32 MFMA, 48KB LDS.
// Subtile LDS (24KB): A rows 128B = [hi 4x16B | lo 4x16B], slot ^ (row&7)
// swizzle (proven 0 conflicts); B rows 64B hi-only, slot = q ^ ((row>>1)&3).
// Loop (32 iters): {sync; 12 gload_lds; sync; sub0 reads+32 MFMA;
// sub1 reads+32 MFMA} -- ONE vmcnt drain per 64-K (halved vs BK=32).
// Fused LSTM epilogue (h_lo no longer produced).
// ---------------------------------------------------------------------------
__global__ __launch_bounds__(256, 2) void k_gate_gemm(
    const char* __restrict__ Ahi, const char* __restrict__ Alo,
    const char* __restrict__ Bh,
    const float* __restrict__ bias,
    const float* __restrict__ cell,
    float* __restrict__ out0,
    _Float16* __restrict__ hhi) {
    __shared__ char smem[49152];  // 2 subtiles x (A 16KB | B 8KB)

    const int tid  = threadIdx.x;
    const int lane = tid & 63;
    const int w    = tid >> 6;           // wave 0..3
    const int wr   = (w >> 1) * 64;      // wave M offset
    const int wc   = (w & 1) * 64;       // wave N offset
    const int fr   = lane & 15;
    const int q    = lane >> 4;
    const int sw   = lane & 7;
    const int m0   = blockIdx.y * 128;
    const int n0   = blockIdx.x * 128;

    f32x4 acc[4][4];
    #pragma unroll
    for (int i = 0; i < 4; i++)
        #pragma unroll
        for (int j = 0; j < 4; j++) acc[i][j] = (f32x4){0.f, 0.f, 0.f, 0.f};

    // --- staging sources (global side carries the swizzle; linear LDS dest) ---
    const int sr = tid >> 3;               // A: row within 32-row chunk (0..31)
    const int s2 = (tid & 7) ^ (sr & 7);   // A: logical slot (part*4 + kchunk)
    const char* As = ((s2 < 4) ? Ahi : Alo)
                     + (int64_t)(m0 + sr) * 4096 + (s2 & 3) * 16;
    const int brow = tid >> 2;             // B: row within 64-row chunk (0..63)
    const int bg   = (tid & 3) ^ ((tid >> 3) & 3);  // B: k-chunk for this slot
    const char* Bs = Bh + (int64_t)(n0 + brow) * 4096 + bg * 16;

    // --- ds_read side swizzles ---
    const unsigned hiSlot = (unsigned)((q ^ sw) << 4);
    const unsigned loSlot = (unsigned)(((q + 4) ^ sw) << 4);
    const unsigned bSlot  = (unsigned)((q ^ ((fr >> 1) & 3)) << 4);

    for (int t = 0; t < 32; ++t) {       // 64-K per iteration
        __syncthreads();   // previous-iteration LDS readers done
        #pragma unroll
        for (int s = 0; s < 2; ++s) {
            const int kk = 2 * t + s;    // 32-K step index
            #pragma unroll
            for (int i = 0; i < 4; i++)
                gload_lds16(As + (int64_t)i * 32 * 4096 + kk * 64,
                            smem + s * 24576 + i * 4096 + tid * 16);
            #pragma unroll
            for (int i = 0; i < 2; i++)
                gload_lds16(Bs + (int64_t)i * 64 * 4096 + kk * 64,
                            smem + s * 24576 + 16384 + i * 4096 + tid * 16);
        }
        __syncthreads();   // loads landed (compiler drains vmcnt once per 64-K)

        #pragma unroll
        for (int s = 0; s < 2; ++s) {
            const char* sA = smem + s * 24576;
            const char* sB = sA + 16384;
            f16x8 ah[4], al[4], bh[4];
            #pragma unroll
            for (int mi = 0; mi < 4; mi++) {
                const char* rp = sA + (wr + mi * 16 + fr) * 128;
                ah[mi] = *(const f16x8*)(rp + hiSlot);
                al[mi] = *(const f16x8*)(rp + loSlot);
            }
            #pragma unroll
            for (int ni = 0; ni < 4; ni++)
                bh[ni] = *(const f16x8*)(sB + (wc + ni * 16 + fr) * 64 + bSlot);

            #pragma unroll
            for (int ni = 0; ni < 4; ni++)
                #pragma unroll
                for (int mi = 0; mi < 4; mi++)
                    acc[mi][ni] = mfma16(ah[mi], bh[ni], acc[mi][ni]);
            #pragma unroll
            for (int ni = 0; ni < 4; ni++)
                #pragma unroll
                for (int mi = 0; mi < 4; mi++)
                    acc[mi][ni] = mfma16(al[mi], bh[ni], acc[mi][ni]);
        }
    }

    // ---- fused LSTM epilogue (16x16 C layout: col=lane&15, row=q*4+j) ----
    const int lb = lane & ~3;  // quad lanes lb..lb+3 = gates f,i,c,o of one h
    const int64_t OFF_H = (int64_t)B_DIM * H_DIM;
    const int64_t OFF_C = (int64_t)2 * B_DIM * H_DIM;
    const int g = lane & 3;
    #pragma unroll
    for (int mi = 0; mi < 4; mi++)
        #pragma unroll
        for (int ni = 0; ni < 4; ni++) {
            int col = n0 + wc + ni * 16 + fr;  // n' = 4h+g
            int h = col >> 2;
            float bb = bias[col];
            int rowb = m0 + wr + mi * 16 + q * 4;
            #pragma unroll
            for (int j = 0; j < 4; j++) {
                float v = acc[mi][ni][j] + bb;
                float a = (g == 2) ? tanhf(v) : 1.0f / (1.0f + expf(-v));
                float fg = __shfl(a, lb + 0, 64);
                float ig = __shfl(a, lb + 1, 64);
                float ct = __shfl(a, lb + 2, 64);
                float og = __shfl(a, lb + 3, 64);
                int row = rowb + j;
                int64_t o = (int64_t)row * H_DIM + h;
                float cn = fg * cell[o] + ig * ct;
                float hn = og * tanhf(cn);
                if (g == 0) {
                    out0[OFF_C + o] = cn;
                } else if (g == 1) {
                    out0[OFF_H + o] = hn;
                } else if (g == 2) {
                    hhi[o] = (_Float16)hn;
                }
                // g == 3: no h_lo needed (logits GEMM is single-product)
            }
        }
}

// ---------------------------------------------------------------------------
// LOGITS GEMM: fp16 single-product, 128x128 tile, BK=32, 4 waves.
// A = h_hi fp16 [8192][1024]; B = W_h^T fp16 [1024][1024].  Both tiles use
// the 64B-row layout with slot = q ^ ((row>>1)&3) (2-way aliasing = free).
// ---------------------------------------------------------------------------
__global__ __launch_bounds__(256, 2) void k_gemm128(
    const char* __restrict__ Ah, const char* __restrict__ Bh,
    const float* __restrict__ bias,
    float* __restrict__ out0) {
    __shared__ char smem[16384];  // A 8KB | B 8KB

    const int tid  = threadIdx.x;
    const int lane = tid & 63;
    const int w    = tid >> 6;
    const int wr   = (w >> 1) * 64;
    const int wc   = (w & 1) * 64;
    const int m0   = blockIdx.y * 128;
    const int n0   = blockIdx.x * 128;
    const int fr   = lane & 15;
    const int q    = lane >> 4;

    f32x4 acc[4][4];
    #pragma unroll
    for (int i = 0; i < 4; i++)
        #pragma unroll
        for (int j = 0; j < 4; j++) acc[i][j] = (f32x4){0.f, 0.f, 0.f, 0.f};

    const int srow = tid >> 2;             // row within 64-row chunk (0..63)
    const int sg   = (tid & 3) ^ ((tid >> 3) & 3);  // k-chunk for this slot
    const char* Asrc = Ah + (int64_t)(m0 + srow) * 2048 + sg * 16;
    const char* Bsrc = Bh + (int64_t)(n0 + srow) * 2048 + sg * 16;

    const unsigned slot = (unsigned)((q ^ ((fr >> 1) & 3)) << 4);

    for (int t = 0; t < 32; ++t) {   // K=1024, BK=32
        __syncthreads();
        #pragma unroll
        for (int i = 0; i < 2; i++)
            gload_lds16(Asrc + (int64_t)i * 64 * 2048 + t * 64,
                        smem + i * 4096 + tid * 16);
        #pragma unroll
        for (int i = 0; i < 2; i++)
            gload_lds16(Bsrc + (int64_t)i * 64 * 2048 + t * 64,
                        smem + 8192 + i * 4096 + tid * 16);
        __syncthreads();

        f16x8 ah[4], bh[4];
        #pragma unroll
        for (int mi = 0; mi < 4; mi++)
            ah[mi] = *(const f16x8*)(smem + (wr + mi * 16 + fr) * 64 + slot);
        #pragma unroll
        for (int ni = 0; ni < 4; ni++)
            bh[ni] = *(const f16x8*)(smem + 8192 + (wc + ni * 16 + fr) * 64 + slot);

        #pragma unroll
        for (int ni = 0; ni < 4; ni++)
            #pragma unroll
            for (int mi = 0; mi < 4; mi++)
                acc[mi][ni] = mfma16(ah[mi], bh[ni], acc[mi][ni]);
    }

    #pragma unroll
    for (int mi = 0; mi < 4; mi++)
        #pragma unroll
        for (int ni = 0; ni < 4; ni++) {
            int col = n0 + wc + ni * 16 + fr;
            int rowb = m0 + wr + mi * 16 + q * 4;
            float bb = bias[col];
            #pragma unroll
            for (int j = 0; j < 4; j++)
                out0[(int64_t)(rowb + j) * 1024 + col] = acc[mi][ni][j] + bb;
        }
}

// ---------------------------------------------------------------------------
// Row-wise log_softmax over [8192][1024]: one block per row.
// ---------------------------------------------------------------------------
__global__ __launch_bounds__(256) void k_logsoftmax(
    const float* __restrict__ logits, float* __restrict__ out) {
    const int row = blockIdx.x;
    const int t = threadIdx.x;
    const float* x = logits + (int64_t)row * 1024;
    float4 v = *(const float4*)(x + t * 4);

    float m = fmaxf(fmaxf(v.x, v.y), fmaxf(v.z, v.w));
    #pragma unroll
    for (int off = 1; off < 64; off <<= 1) m = fmaxf(m, __shfl_xor(m, off, 64));
    __shared__ float sm[4];
    __shared__ float ssum[4];
    int ln = t & 63, wv = t >> 6;
    if (ln == 0) sm[wv] = m;
    __syncthreads();
    m = fmaxf(fmaxf(sm[0], sm[1]), fmaxf(sm[2], sm[3]));

    float s = expf(v.x - m) + expf(v.y - m) + expf(v.z - m) + expf(v.w - m);
    #pragma unroll
    for (int off = 1; off < 64; off <<= 1) s += __shfl_xor(s, off, 64);
    if (ln == 0) ssum[wv] = s;
    __syncthreads();
    s = ssum[0] + ssum[1] + ssum[2] + ssum[3];

    float lse = m + logf(s);
    float4 o;
    o.x = v.x - lse; o.y = v.y - lse; o.z = v.z - lse; o.w = v.w - lse;
    *(float4*)(out + (int64_t)row * 1024 + t * 4) = o;
}

// ---------------------------------------------------------------------------
extern "C" void kernel_launch(void* const* d_in, const int* in_sizes, int n_in,
                              void* d_out, int out_size, void* d_ws, size_t ws_size,
                              hipStream_t stream) {
    const float* input  = (const float*)d_in[0];
    const float* hidden = (const float*)d_in[1];
    const float* cell   = (const float*)d_in[2];
    const float* W_f = (const float*)d_in[3];
    const float* U_f = (const float*)d_in[4];
    const float* b_f = (const float*)d_in[5];
    const float* W_i = (const float*)d_in[6];
    const float* U_i = (const float*)d_in[7];
    const float* b_i = (const float*)d_in[8];
    const float* W_c = (const float*)d_in[9];
    const float* U_c = (const float*)d_in[10];
    const float* b_c = (const float*)d_in[11];
    const float* W_o = (const float*)d_in[12];
    const float* U_o = (const float*)d_in[13];
    const float* b_o = (const float*)d_in[14];
    const float* W_h = (const float*)d_in[15];
    const float* b_h = (const float*)d_in[16];
    float* out = (float*)d_out;

    char* ws = (char*)d_ws;
    unsigned short* xhi  = (unsigned short*)(ws);               // 32 MB
    unsigned short* xlo  = (unsigned short*)(ws + 33554432);    // 32 MB
    unsigned short* wuhi = (unsigned short*)(ws + 67108864);    // 16 MB
    _Float16*       hhi  = (_Float16*)(ws + 83886080);          // 16 MB
    unsigned short* whh  = (unsigned short*)(ws + 117440512);   // 2 MB
    float*          bias4 = (float*)(ws + 119537664);           // 16 KB
    float*          logits = (float*)(ws);                      // aliases X
    if (ws_size < (size_t)119554048) return;

    k_split_x<<<2048, 256, 0, stream>>>(input, hidden, xhi, xlo);
    k_trans_all<<<dim3(16, 16, 8), 256, 0, stream>>>(
        W_f, W_i, W_c, W_o, U_f, U_i, U_c, U_o, wuhi);
    k_trans_wh<<<dim3(16, 16), 256, 0, stream>>>(W_h, whh);
    k_pack_bias<<<16, 256, 0, stream>>>(b_f, b_i, b_c, b_o, bias4);

    // gates GEMM + fused LSTM epilogue: M=8192, N'=4096, K=2048, 2048 blocks
    k_gate_gemm<<<dim3(32, 64), 256, 0, stream>>>(
        (const char*)xhi, (const char*)xlo, (const char*)wuhi,
        bias4, cell, out, hhi);

    // logits GEMM: M=8192, N=1024, K=1024 (single-product)
    k_gemm128<<<dim3(8, 64), 256, 0, stream>>>(
        (const char*)hhi, (const char*)whh, b_h, logits);

    k_logsoftmax<<<8192, 256, 0, stream>>>(logits, out);
}

// Round 13
// 335.991 us; speedup vs baseline: 3.0211x; 1.3647x over previous
//
#include <hip/hip_runtime.h>
#include <hip/hip_bf16.h>
#include <cstdint>

// ---------------------------------------------------------------------------
// LSTM cell fused forward on MI355X (gfx950).
//   gates = [input|hidden] @ [W;U] + b  -- single-product fp16 emulation:
//     x*W ~= fp16(x) * fp16(W)   (fp32 MFMA accumulate)
//   gate GEMM: m97-structure 128^2, BK=64 (2 x BK32 subtiles), 4 waves,
//              32KB LDS (5 blocks/CU TLP), proven zero-conflict 64B-row swizzle
//   elementwise LSTM epilogue fused; logits = h_hi @ W_h + b_h (1-product);
//   log_softmax row-wise.
// ---------------------------------------------------------------------------

#define B_DIM   8192
#define K1      2048
#define H_DIM   1024

typedef __attribute__((ext_vector_type(8))) _Float16 f16x8;
typedef __attribute__((ext_vector_type(4))) float    f32x4;

__device__ __forceinline__ unsigned short f2h_bits(float x) {
    _Float16 h = (_Float16)x;
    return __builtin_bit_cast(unsigned short, h);
}

__device__ __forceinline__ void gload_lds16(const void* g, void* l) {
    __builtin_amdgcn_global_load_lds(
        (const __attribute__((address_space(1))) void*)g,
        (__attribute__((address_space(3))) void*)l, 16, 0, 0);
}

__device__ __forceinline__ f32x4 mfma16(f16x8 a, f16x8 b, f32x4 c) {
    return __builtin_amdgcn_mfma_f32_16x16x32_f16(a, b, c, 0, 0, 0);
}

// ---------------------------------------------------------------------------
// Pack X = [input | hidden] (row-major [8192][2048]) into fp16.
// ---------------------------------------------------------------------------
__global__ __launch_bounds__(256) void k_split_x(
    const float* __restrict__ input, const float* __restrict__ hidden,
    unsigned short* __restrict__ xhi) {
    const int64_t n4 = (int64_t)B_DIM * K1 / 4;
    for (int64_t i = (int64_t)blockIdx.x * blockDim.x + threadIdx.x; i < n4;
         i += (int64_t)gridDim.x * blockDim.x) {
        int64_t e = i * 4;
        int row = (int)(e >> 11);
        int col = (int)(e & 2047);
        const float* src = (col < 1024) ? (input + (int64_t)row * 1024 + col)
                                        : (hidden + (int64_t)row * 1024 + (col - 1024));
        float4 v = *(const float4*)src;
        ushort4 hv;
        hv.x = f2h_bits(v.x);
        hv.y = f2h_bits(v.y);
        hv.z = f2h_bits(v.z);
        hv.w = f2h_bits(v.w);
        *(ushort4*)(xhi + e) = hv;
    }
}

// ---------------------------------------------------------------------------
// Fused transpose of all 8 gate weights into wuhi[n'=4h+g][k] fp16.
// blockIdx.z: 0-3 = W_{f,i,c,o} (koff 0), 4-7 = U_{f,i,c,o} (koff 1024).
// ---------------------------------------------------------------------------
__global__ __launch_bounds__(256) void k_trans_all(
    const float* __restrict__ W_f, const float* __restrict__ W_i,
    const float* __restrict__ W_c, const float* __restrict__ W_o,
    const float* __restrict__ U_f, const float* __restrict__ U_i,
    const float* __restrict__ U_c, const float* __restrict__ U_o,
    unsigned short* __restrict__ wuhi) {
    const int z = blockIdx.z;
    const float* src;
    if      (z == 0) src = W_f;
    else if (z == 1) src = W_i;
    else if (z == 2) src = W_c;
    else if (z == 3) src = W_o;
    else if (z == 4) src = U_f;
    else if (z == 5) src = U_i;
    else if (z == 6) src = U_c;
    else             src = U_o;
    const int ng = z & 3, koff = (z >> 2) * 1024;

    __shared__ float t[64][65];
    const int h0 = blockIdx.x * 64;
    const int k0 = blockIdx.y * 64;
    const int tx = threadIdx.x & 63, ty = threadIdx.x >> 6;
    #pragma unroll
    for (int r = ty; r < 64; r += 4)
        t[r][tx] = src[(int64_t)(k0 + r) * 1024 + h0 + tx];
    __syncthreads();
    #pragma unroll
    for (int r = ty; r < 64; r += 4) {
        float v = t[tx][r];
        int np = (h0 + r) * 4 + ng;
        wuhi[(int64_t)np * 2048 + koff + k0 + tx] = f2h_bits(v);
    }
}

// W_h [1024x1024] (k-major) -> whh[n][k] fp16.
__global__ __launch_bounds__(256) void k_trans_wh(
    const float* __restrict__ src, unsigned short* __restrict__ whh) {
    __shared__ float t[64][65];
    const int h0 = blockIdx.x * 64;
    const int k0 = blockIdx.y * 64;
    const int tx = threadIdx.x & 63, ty = threadIdx.x >> 6;
    #pragma unroll
    for (int r = ty; r < 64; r += 4)
        t[r][tx] = src[(int64_t)(k0 + r) * 1024 + h0 + tx];
    __syncthreads();
    #pragma unroll
    for (int r = ty; r < 64; r += 4)
        whh[(int64_t)(h0 + r) * 1024 + k0 + tx] = f2h_bits(t[tx][r]);
}

// bias4[n'] = b_g[h], n' = 4h+g
__global__ __launch_bounds__(256) void k_pack_bias(
    const float* __restrict__ bf_, const float* __restrict__ bi_,
    const float* __restrict__ bc_, const float* __restrict__ bo_,
    float* __restrict__ bias4) {
    int n = blockIdx.x * 256 + threadIdx.x;
    if (n < 4096) {
        int g = n & 3, h = n >> 2;
        const float* p = (g == 0) ? bf_ : (g == 1) ? bi_ : (g == 2) ? bc_ : bo_;
        bias4[n] = p[h];
    }
}

// ---------------------------------------------------------------------------
// GATE GEMM: single-product fp16, m97 structure.  128x128 tile, BK=64 as two
// BK32 subtiles, 4 waves (2M x 2N, 64x64 each), 16x16x32 MFMA, 32KB LDS.
// Subtile LDS (16KB): A rows 64B + B rows 64B, slot = q ^ ((row>>1)&3)
// (2-way bank aliasing = free; measured 0 conflicts in R12 on B).
// Loop (32 iters): {sync; 8 gload_lds; sync; sub0 8 reads+16 MFMA;
// sub1 8 reads+16 MFMA} -- one vmcnt drain per 64-K.  Fused LSTM epilogue.
// ---------------------------------------------------------------------------
__global__ __launch_bounds__(256, 2) void k_gate_gemm(
    const char* __restrict__ Ah, const char* __restrict__ Bh,
    const float* __restrict__ bias,
    const float* __restrict__ cell,
    float* __restrict__ out0,
    _Float16* __restrict__ hhi) {
    __shared__ char smem[32768];  // 2 subtiles x (A 8KB | B 8KB)

    const int tid  = threadIdx.x;
    const int lane = tid & 63;
    const int w    = tid >> 6;           // wave 0..3
    const int wr   = (w >> 1) * 64;      // wave M offset
    const int wc   = (w & 1) * 64;       // wave N offset
    const int fr   = lane & 15;
    const int q    = lane >> 4;
    const int m0   = blockIdx.y * 128;
    const int n0   = blockIdx.x * 128;

    f32x4 acc[4][4];
    #pragma unroll
    for (int i = 0; i < 4; i++)
        #pragma unroll
        for (int j = 0; j < 4; j++) acc[i][j] = (f32x4){0.f, 0.f, 0.f, 0.f};

    // --- staging sources (global side carries the swizzle; linear LDS dest) ---
    const int srow = tid >> 2;             // row within 64-row chunk (0..63)
    const int sg   = (tid & 3) ^ ((tid >> 3) & 3);  // logical k-chunk
    const char* As = Ah + (int64_t)(m0 + srow) * 4096 + sg * 16;
    const char* Bs = Bh + (int64_t)(n0 + srow) * 4096 + sg * 16;

    // --- ds_read side swizzle (same for A and B: 64B rows) ---
    const unsigned slot = (unsigned)((q ^ ((fr >> 1) & 3)) << 4);

    for (int t = 0; t < 32; ++t) {       // 64-K per iteration
        __syncthreads();   // previous-iteration LDS readers done
        #pragma unroll
        for (int s = 0; s < 2; ++s) {
            const int kk = 2 * t + s;    // 32-K step index
            #pragma unroll
            for (int i = 0; i < 2; i++)
                gload_lds16(As + (int64_t)i * 64 * 4096 + kk * 64,
                            smem + s * 16384 + i * 4096 + tid * 16);
            #pragma unroll
            for (int i = 0; i < 2; i++)
                gload_lds16(Bs + (int64_t)i * 64 * 4096 + kk * 64,
                            smem + s * 16384 + 8192 + i * 4096 + tid * 16);
        }
        __syncthreads();   // loads landed (one vmcnt drain per 64-K)

        #pragma unroll
        for (int s = 0; s < 2; ++s) {
            const char* sA = smem + s * 16384;
            const char* sB = sA + 8192;
            f16x8 ah[4], bh[4];
            #pragma unroll
            for (int mi = 0; mi < 4; mi++)
                ah[mi] = *(const f16x8*)(sA + (wr + mi * 16 + fr) * 64 + slot);
            #pragma unroll
            for (int ni = 0; ni < 4; ni++)
                bh[ni] = *(const f16x8*)(sB + (wc + ni * 16 + fr) * 64 + slot);

            #pragma unroll
            for (int ni = 0; ni < 4; ni++)
                #pragma unroll
                for (int mi = 0; mi < 4; mi++)
                    acc[mi][ni] = mfma16(ah[mi], bh[ni], acc[mi][ni]);
        }
    }

    // ---- fused LSTM epilogue (16x16 C layout: col=lane&15, row=q*4+j) ----
    const int lb = lane & ~3;  // quad lanes lb..lb+3 = gates f,i,c,o of one h
    const int64_t OFF_H = (int64_t)B_DIM * H_DIM;
    const int64_t OFF_C = (int64_t)2 * B_DIM * H_DIM;
    const int g = lane & 3;
    #pragma unroll
    for (int mi = 0; mi < 4; mi++)
        #pragma unroll
        for (int ni = 0; ni < 4; ni++) {
            int col = n0 + wc + ni * 16 + fr;  // n' = 4h+g
            int h = col >> 2;
            float bb = bias[col];
            int rowb = m0 + wr + mi * 16 + q * 4;
            #pragma unroll
            for (int j = 0; j < 4; j++) {
                float v = acc[mi][ni][j] + bb;
                float a = (g == 2) ? tanhf(v) : 1.0f / (1.0f + expf(-v));
                float fg = __shfl(a, lb + 0, 64);
                float ig = __shfl(a, lb + 1, 64);
                float ct = __shfl(a, lb + 2, 64);
                float og = __shfl(a, lb + 3, 64);
                int row = rowb + j;
                int64_t o = (int64_t)row * H_DIM + h;
                float cn = fg * cell[o] + ig * ct;
                float hn = og * tanhf(cn);
                if (g == 0) {
                    out0[OFF_C + o] = cn;
                } else if (g == 1) {
                    out0[OFF_H + o] = hn;
                } else if (g == 2) {
                    hhi[o] = (_Float16)hn;
                }
            }
        }
}

// ---------------------------------------------------------------------------
// LOGITS GEMM: fp16 single-product, 128x128 tile, BK=32, 4 waves.
// A = h_hi fp16 [8192][1024]; B = W_h^T fp16 [1024][1024].  64B-row layout,
// slot = q ^ ((row>>1)&3).
// ---------------------------------------------------------------------------
__global__ __launch_bounds__(256, 2) void k_gemm128(
    const char* __restrict__ Ah, const char* __restrict__ Bh,
    const float* __restrict__ bias,
    float* __restrict__ out0) {
    __shared__ char smem[16384];  // A 8KB | B 8KB

    const int tid  = threadIdx.x;
    const int lane = tid & 63;
    const int w    = tid >> 6;
    const int wr   = (w >> 1) * 64;
    const int wc   = (w & 1) * 64;
    const int m0   = blockIdx.y * 128;
    const int n0   = blockIdx.x * 128;
    const int fr   = lane & 15;
    const int q    = lane >> 4;

    f32x4 acc[4][4];
    #pragma unroll
    for (int i = 0; i < 4; i++)
        #pragma unroll
        for (int j = 0; j < 4; j++) acc[i][j] = (f32x4){0.f, 0.f, 0.f, 0.f};

    const int srow = tid >> 2;             // row within 64-row chunk (0..63)
    const int sg   = (tid & 3) ^ ((tid >> 3) & 3);  // logical k-chunk
    const char* Asrc = Ah + (int64_t)(m0 + srow) * 2048 + sg * 16;
    const char* Bsrc = Bh + (int64_t)(n0 + srow) * 2048 + sg * 16;

    const unsigned slot = (unsigned)((q ^ ((fr >> 1) & 3)) << 4);

    for (int t = 0; t < 32; ++t) {   // K=1024, BK=32
        __syncthreads();
        #pragma unroll
        for (int i = 0; i < 2; i++)
            gload_lds16(Asrc + (int64_t)i * 64 * 2048 + t * 64,
                        smem + i * 4096 + tid * 16);
        #pragma unroll
        for (int i = 0; i < 2; i++)
            gload_lds16(Bsrc + (int64_t)i * 64 * 2048 + t * 64,
                        smem + 8192 + i * 4096 + tid * 16);
        __syncthreads();

        f16x8 ah[4], bh[4];
        #pragma unroll
        for (int mi = 0; mi < 4; mi++)
            ah[mi] = *(const f16x8*)(smem + (wr + mi * 16 + fr) * 64 + slot);
        #pragma unroll
        for (int ni = 0; ni < 4; ni++)
            bh[ni] = *(const f16x8*)(smem + 8192 + (wc + ni * 16 + fr) * 64 + slot);

        #pragma unroll
        for (int ni = 0; ni < 4; ni++)
            #pragma unroll
            for (int mi = 0; mi < 4; mi++)
                acc[mi][ni] = mfma16(ah[mi], bh[ni], acc[mi][ni]);
    }

    #pragma unroll
    for (int mi = 0; mi < 4; mi++)
        #pragma unroll
        for (int ni = 0; ni < 4; ni++) {
            int col = n0 + wc + ni * 16 + fr;
            int rowb = m0 + wr + mi * 16 + q * 4;
            float bb = bias[col];
            #pragma unroll
            for (int j = 0; j < 4; j++)
                out0[(int64_t)(rowb + j) * 1024 + col] = acc[mi][ni][j] + bb;
        }
}

// ---------------------------------------------------------------------------
// Row-wise log_softmax over [8192][1024]: one block per row.
// ---------------------------------------------------------------------------
__global__ __launch_bounds__(256) void k_logsoftmax(
    const float* __restrict__ logits, float* __restrict__ out) {
    const int row = blockIdx.x;
    const int t = threadIdx.x;
    const float* x = logits + (int64_t)row * 1024;
    float4 v = *(const float4*)(x + t * 4);

    float m = fmaxf(fmaxf(v.x, v.y), fmaxf(v.z, v.w));
    #pragma unroll
    for (int off = 1; off < 64; off <<= 1) m = fmaxf(m, __shfl_xor(m, off, 64));
    __shared__ float sm[4];
    __shared__ float ssum[4];
    int ln = t & 63, wv = t >> 6;
    if (ln == 0) sm[wv] = m;
    __syncthreads();
    m = fmaxf(fmaxf(sm[0], sm[1]), fmaxf(sm[2], sm[3]));

    float s = expf(v.x - m) + expf(v.y - m) + expf(v.z - m) + expf(v.w - m);
    #pragma unroll
    for (int off = 1; off < 64; off <<= 1) s += __shfl_xor(s, off, 64);
    if (ln == 0) ssum[wv] = s;
    __syncthreads();
    s = ssum[0] + ssum[1] + ssum[2] + ssum[3];

    float lse = m + logf(s);
    float4 o;
    o.x = v.x - lse; o.y = v.y - lse; o.z = v.z - lse; o.w = v.w - lse;
    *(float4*)(out + (int64_t)row * 1024 + t * 4) = o;
}

// ---------------------------------------------------------------------------
extern "C" void kernel_launch(void* const* d_in, const int* in_sizes, int n_in,
                              void* d_out, int out_size, void* d_ws, size_t ws_size,
                              hipStream_t stream) {
    const float* input  = (const float*)d_in[0];
    const float* hidden = (const float*)d_in[1];
    const float* cell   = (const float*)d_in[2];
    const float* W_f = (const float*)d_in[3];
    const float* U_f = (const float*)d_in[4];
    const float* b_f = (const float*)d_in[5];
    const float* W_i = (const float*)d_in[6];
    const float* U_i = (const float*)d_in[7];
    const float* b_i = (const float*)d_in[8];
    const float* W_c = (const float*)d_in[9];
    const float* U_c = (const float*)d_in[10];
    const float* b_c = (const float*)d_in[11];
    const float* W_o = (const float*)d_in[12];
    const float* U_o = (const float*)d_in[13];
    const float* b_o = (const float*)d_in[14];
    const float* W_h = (const float*)d_in[15];
    const float* b_h = (const float*)d_in[16];
    float* out = (float*)d_out;

    char* ws = (char*)d_ws;
    unsigned short* xhi  = (unsigned short*)(ws);               // 32 MB
    unsigned short* wuhi = (unsigned short*)(ws + 67108864);    // 16 MB
    _Float16*       hhi  = (_Float16*)(ws + 83886080);          // 16 MB
    unsigned short* whh  = (unsigned short*)(ws + 117440512);   // 2 MB
    float*          bias4 = (float*)(ws + 119537664);           // 16 KB
    float*          logits = (float*)(ws + 33554432);           // 32 MB (free region)
    if (ws_size < (size_t)119554048) return;

    k_split_x<<<2048, 256, 0, stream>>>(input, hidden, xhi);
    k_trans_all<<<dim3(16, 16, 8), 256, 0, stream>>>(
        W_f, W_i, W_c, W_o, U_f, U_i, U_c, U_o, wuhi);
    k_trans_wh<<<dim3(16, 16), 256, 0, stream>>>(W_h, whh);
    k_pack_bias<<<16, 256, 0, stream>>>(b_f, b_i, b_c, b_o, bias4);

    // gates GEMM + fused LSTM epilogue: M=8192, N'=4096, K=2048, 2048 blocks
    k_gate_gemm<<<dim3(32, 64), 256, 0, stream>>>(
        (const char*)xhi, (const char*)wuhi, bias4, cell, out, hhi);

    // logits GEMM: M=8192, N=1024, K=1024 (single-product)
    k_gemm128<<<dim3(8, 64), 256, 0, stream>>>(
        (const char*)hhi, (const char*)whh, b_h, logits);

    k_logsoftmax<<<8192, 256, 0, stream>>>(logits, out);
}